// Round 5
// baseline (412.013 us; speedup 1.0000x reference)
//
#include <hip/hip_runtime.h>

#define NTOK 2048
#define HID 4096
#define NOUT 4096
#define NLORA 16
#define RANK 16

typedef float floatx4 __attribute__((ext_vector_type(4)));
typedef __bf16 bf16x8 __attribute__((ext_vector_type(8)));

__device__ __forceinline__ unsigned short f2b(float f) {
  unsigned int u = __float_as_uint(f);
  u += 0x7FFFu + ((u >> 16) & 1u);   // round-to-nearest-even
  return (unsigned short)(u >> 16);
}
__device__ __forceinline__ float b2f(unsigned short u) {
  return __uint_as_float(((unsigned int)u) << 16);
}
__device__ __forceinline__ unsigned int pk2(float a, float b) {
  return (unsigned int)f2b(a) | ((unsigned int)f2b(b) << 16);
}

// async global->LDS, 16 B/lane; LDS dest is wave-uniform base (+ lane*16 in HW)
__device__ __forceinline__ void gld16(const char* g, char* l) {
  __builtin_amdgcn_global_load_lds(
      (const __attribute__((address_space(1))) unsigned int*)g,
      (__attribute__((address_space(3))) unsigned int*)l,
      16, 0, 0);
}

// ---- inline per-wave dtype detection ----
__device__ __forceinline__ int detect_bf16(const void* xraw) {
  const int lane = threadIdx.x & 63;
  const int e = (((const unsigned short*)xraw)[2 * lane] >> 7) & 0xFF;
  const unsigned long long wild = __ballot(e < 96 || e > 159);
  return wild == 0ull;
}
__device__ __forceinline__ int detect_i64(const int* idxraw) {
  const int lane = threadIdx.x & 63;
  const unsigned long long nz = __ballot((lane & 1) && idxraw[lane] != 0);
  return nz == 0ull;
}

// ============ prep: axall slices (+X conversion side-effect) + W conversion ==
// (unchanged except: block 0 zeroes the split-K tile counters, which the
// same-stream gemm launch then observes — stream order is a full barrier)
__global__ __launch_bounds__(256) void prep_kernel(
    const void* __restrict__ xv, const void* __restrict__ wv,
    const void* __restrict__ lav,
    unsigned short* __restrict__ xb, unsigned short* __restrict__ wb,
    float* __restrict__ axpart, int nks, int full, int* __restrict__ cnt) {
  const int tid = threadIdx.x;
  if (cnt && blockIdx.x == 0 && tid < 128) cnt[tid] = 0;
  const int isb = detect_bf16(xv);
  const int AXB = 32 * nks;
  if (blockIdx.x >= AXB) {
    if (isb || !full) return;
    const int W8 = NOUT * HID / 8;
    const int cb = blockIdx.x - AXB;
    for (int i = cb * 256 + tid; i < W8; i += 2048 * 256) {
      const float4 a = ((const float4*)wv)[2 * i];
      const float4 b = ((const float4*)wv)[2 * i + 1];
      uint4 p;
      p.x = pk2(a.x, a.y); p.y = pk2(a.z, a.w);
      p.z = pk2(b.x, b.y); p.w = pk2(b.z, b.w);
      ((uint4*)wb)[i] = p;
    }
    return;
  }
  __shared__ char sm[16384];           // X 8KB @0, Acat 8KB @8192 (64B rows)
  const int b = blockIdx.x;
  const int tt = b & 15, nt = (b >> 4) & 1, ks = b >> 5;
  const int t0 = tt * 128, n0 = nt * 128;
  const int kslice = HID / nks;
  const int k0 = ks * kslice;
  const int wave = tid >> 6, lane = tid & 63;
  const int isx = tid < 128;
  const int row = isx ? tid : tid - 128;
  const size_t gbase = (size_t)((isx ? t0 : n0) + row) * HID + k0;
  const float* srcF = (isx ? (const float*)xv : (const float*)lav) + gbase;
  const unsigned short* srcB =
      (isx ? (const unsigned short*)xv : (const unsigned short*)lav) + gbase;
  char* ldsrow = sm + (isx ? 0 : 8192) + row * 64;
  const int prm = (tid >> 1) & 3;      // (row>>1)&3
  const int wrxb = (isx && nt == 0 && !isb && full);
  unsigned short* xbrow = xb + (size_t)(t0 + row) * HID + k0;

  const int wr = (wave >> 1) * 64, wc = (wave & 1) * 64;
  const int fm = lane & 15, fq = lane >> 4;
  const int sw2 = (fm >> 1) & 3;
  int aO[4], bO[4];
  #pragma unroll
  for (int i = 0; i < 4; ++i) {
    aO[i] = (wr + i * 16 + fm) * 64 + ((fq ^ sw2) << 4);
    bO[i] = 8192 + (wc + i * 16 + fm) * 64 + ((fq ^ sw2) << 4);
  }
  floatx4 acc[4][4];
  #pragma unroll
  for (int i = 0; i < 4; ++i)
    #pragma unroll
    for (int j = 0; j < 4; ++j) acc[i][j] = (floatx4){0.f, 0.f, 0.f, 0.f};

  const int NIT = kslice / 32;
  for (int it = 0; it < NIT; ++it) {
    uint4 w[4];
    if (isb) {
      const uint4* s4 = (const uint4*)(srcB + it * 32);
      #pragma unroll
      for (int g = 0; g < 4; ++g) w[g] = s4[g];
    } else {
      const float4* s4 = (const float4*)(srcF + it * 32);
      #pragma unroll
      for (int g = 0; g < 4; ++g) {
        const float4 f0 = s4[2 * g], f1 = s4[2 * g + 1];
        w[g].x = pk2(f0.x, f0.y); w[g].y = pk2(f0.z, f0.w);
        w[g].z = pk2(f1.x, f1.y); w[g].w = pk2(f1.z, f1.w);
      }
      if (wrxb) {
        uint4* d = (uint4*)(xbrow + it * 32);
        #pragma unroll
        for (int g = 0; g < 4; ++g) d[g] = w[g];
      }
    }
    #pragma unroll
    for (int g = 0; g < 4; ++g)
      *(uint4*)(ldsrow + ((g ^ prm) << 4)) = w[g];
    __syncthreads();
    bf16x8 af[4], bfv[4];
    #pragma unroll
    for (int i = 0; i < 4; ++i) af[i] = *(const bf16x8*)(sm + aO[i]);
    #pragma unroll
    for (int j = 0; j < 4; ++j) bfv[j] = *(const bf16x8*)(sm + bO[j]);
    #pragma unroll
    for (int i = 0; i < 4; ++i)
      #pragma unroll
      for (int j = 0; j < 4; ++j)
        acc[i][j] = __builtin_amdgcn_mfma_f32_16x16x32_bf16(af[i], bfv[j], acc[i][j], 0, 0, 0);
    __syncthreads();
  }
  const int c = lane & 15, rr = (lane >> 4) * 4;
  #pragma unroll
  for (int i = 0; i < 4; ++i)
    #pragma unroll
    for (int r = 0; r < 4; ++r) {
      const int t = t0 + wr + i * 16 + rr + r;
      float* dst = axpart + ((size_t)ks * NTOK + t) * 256 + n0 + wc;
      #pragma unroll
      for (int j = 0; j < 4; ++j) dst[j * 16 + c] = acc[i][j][r];
    }
}

// ============ K-SPLIT main GEMM + last-block-fused reduce/epilogue ===========
// K-loop identical to R4's proven 69-us gemm_ks (256x256 tile, 8 waves of
// 128x64, depth-2 counted vmcnt, 3x32KB buffers, 0 bank conflicts).
// NEW: split-K reduction fused via the canonical tile-counter protocol:
//   both kh-blocks store their f32 partial -> __threadfence (release) ->
//   atomicAdd on a per-(t,o)-tile counter (device scope, cross-XCD safe).
//   The SECOND arriver (old==1) acquires, reads only the PARTNER partial
//   (own partial still in registers), folds, and runs the bias+LoRA epilogue
//   + output store. No dispatch-order assumption: the partner provably ran
//   (its counter bump precedes ours in the atomic total order).
__global__ __launch_bounds__(512, 2) void gemm_ks2_kernel(
    const void* __restrict__ x_raw, const void* __restrict__ w_raw,
    const unsigned short* __restrict__ xb_ws, const unsigned short* __restrict__ wb_ws,
    const void* __restrict__ bias_raw, const void* __restrict__ lorab_raw,
    const float* __restrict__ axpart, const int* __restrict__ idxraw,
    int nks, float* __restrict__ P, int* __restrict__ cnt,
    void* __restrict__ outv) {
  __shared__ char smem[98304];  // K-loop: buf b @ b*32768 (A 16K, B 16K)
                                // epilogue: Bl 64K @0, axs 16K @65536, tok @81920
  __shared__ int s_old;
  const int isb = detect_bf16(x_raw);
  const int i64 = detect_i64(idxraw);
  const unsigned short* Xb = isb ? (const unsigned short*)x_raw : xb_ws;
  const unsigned short* Wb = isb ? (const unsigned short*)w_raw : wb_ws;

  const int tid = threadIdx.x;
  const int wave = tid >> 6;
  const int lane = tid & 63;
  // XCD-compact: slot bits [0]=o, [3:1]=t, [4]=kh; per XCD: 2 o-tiles (W slab
  // 4MB = L2), 8 t-tiles, 2 K-halves.
  const int id = blockIdx.x;
  const int xcd = id & 7, slot = id >> 3;           // 0..31
  const int otile = xcd * 2 + (slot & 1);            // 0..15
  const int ttile = (slot >> 1) & 7;                 // 0..7
  const int o0 = otile * 256;
  const int t0 = ttile * 256;
  const int kh = slot >> 4;                          // 0..1
  const int tileidx = ttile * 16 + otile;            // 0..127
  const int wr = (wave >> 2) * 128;   // 2 row-groups of 128
  const int wc = (wave & 3) * 64;     // 4 col-groups of 64

  // staging: wave w covers rows w*32..w*32+31 of A and of B (two 16-row gld16
  // each); granule s = lane covers row s>>2, stored q = tile_q ^ ((row>>1)&3)
  const int q_ = ((lane & 3) ^ ((lane >> 3) & 3)) * 16;
  const int srw = (lane >> 2);
  const char* gA = (const char*)Xb + (size_t)(t0 + wave * 32 + srw) * (HID * 2)
                 + q_ + (size_t)kh * 4096;
  const char* gB = (const char*)Wb + (size_t)(o0 + wave * 32 + srw) * (HID * 2)
                 + q_ + (size_t)kh * 4096;

  const int fm = lane & 15, fq = lane >> 4;
  const int sw2 = (fm >> 1) & 3;
  int aOff[8], bOff[4];
  #pragma unroll
  for (int i = 0; i < 8; ++i)
    aOff[i] = (wr + i * 16 + fm) * 64 + ((fq ^ sw2) << 4);
  #pragma unroll
  for (int j = 0; j < 4; ++j)
    bOff[j] = 16384 + (wc + j * 16 + fm) * 64 + ((fq ^ sw2) << 4);
  floatx4 acc[8][4];
  #pragma unroll
  for (int i = 0; i < 8; ++i)
    #pragma unroll
    for (int j = 0; j < 4; ++j) acc[i][j] = (floatx4){0.f, 0.f, 0.f, 0.f};

#define KSTAGE(K, B) do {                                         \
    const size_t kb_ = (size_t)(K) * 64;                          \
    char* d_ = smem + (B) * 32768 + wave * 2048;                  \
    gld16(gA + kb_,                           d_);                \
    gld16(gA + kb_ + 16 * (size_t)HID * 2,    d_ + 1024);         \
    gld16(gB + kb_,                           d_ + 16384);        \
    gld16(gB + kb_ + 16 * (size_t)HID * 2,    d_ + 17408);        \
  } while (0)

#define KCOMPUTE(B) do {                                                        \
    const char* base_ = smem + (B) * 32768;                                     \
    bf16x8 af[8], bfv[4];                                                       \
    _Pragma("unroll")                                                           \
    for (int i = 0; i < 8; ++i) af[i] = *(const bf16x8*)(base_ + aOff[i]);      \
    _Pragma("unroll")                                                           \
    for (int j = 0; j < 4; ++j) bfv[j] = *(const bf16x8*)(base_ + bOff[j]);     \
    _Pragma("unroll")                                                           \
    for (int i = 0; i < 8; ++i)                                                 \
      _Pragma("unroll")                                                         \
      for (int j = 0; j < 4; ++j)                                               \
        acc[i][j] = __builtin_amdgcn_mfma_f32_16x16x32_bf16(af[i], bfv[j], acc[i][j], 0, 0, 0); \
  } while (0)

  const int KITER = (HID / 2) / 32;   // 64 K-steps per half
  int cb = 0, sb = 2;
  KSTAGE(0, 0);
  KSTAGE(1, 1);
  for (int k = 0; k < KITER - 2; ++k) {
    // 8 gld16/wave outstanding (stages k, k+1); vmcnt(4) => stage k landed.
    asm volatile("s_waitcnt vmcnt(4)" ::: "memory");
    __builtin_amdgcn_s_barrier();
    KSTAGE(k + 2, sb);
    KCOMPUTE(cb);
    cb = (cb == 2) ? 0 : cb + 1;
    sb = (sb == 2) ? 0 : sb + 1;
  }
  asm volatile("s_waitcnt vmcnt(4)" ::: "memory");
  __builtin_amdgcn_s_barrier();
  KCOMPUTE(cb);
  cb = (cb == 2) ? 0 : cb + 1;
  asm volatile("s_waitcnt vmcnt(0)" ::: "memory");
  __builtin_amdgcn_s_barrier();
  KCOMPUTE(cb);
#undef KSTAGE
#undef KCOMPUTE

  // ---- store own f32 partial tile ----
  const int c = lane & 15, rr = (lane >> 4) * 4;
  #pragma unroll
  for (int mi = 0; mi < 8; ++mi) {
    #pragma unroll
    for (int r = 0; r < 4; ++r) {
      const size_t t = t0 + wr + mi * 16 + rr + r;
      float* dst = P + ((size_t)kh * NTOK + t) * NOUT + o0 + wc;
      #pragma unroll
      for (int j = 0; j < 4; ++j) dst[j * 16 + c] = acc[mi][j][r];
    }
  }
  // ---- tile-counter rendezvous (release/acquire via device-scope atomic) ----
  __threadfence();
  __syncthreads();
  if (tid == 0) s_old = atomicAdd(&cnt[tileidx], 1);
  __syncthreads();
  if (s_old == 0) return;          // first arriver: partial published, done
  __threadfence();                 // acquire partner's fenced stores

  // ---- fold partner partial into registers ----
  {
    const int kho = kh ^ 1;
    #pragma unroll
    for (int mi = 0; mi < 8; ++mi) {
      #pragma unroll
      for (int r = 0; r < 4; ++r) {
        const size_t t = t0 + wr + mi * 16 + rr + r;
        const float* src = P + ((size_t)kho * NTOK + t) * NOUT + o0 + wc;
        #pragma unroll
        for (int j = 0; j < 4; ++j) acc[mi][j][r] += src[j * 16 + c];
      }
    }
  }

  // ---- epilogue: ax table + tok table in LDS (256 tokens, 512 threads) ----
  {
    const int t_l = tid >> 1, h8 = (tid & 1) * 8;
    const int t = t0 + t_l;
    int l = i64 ? idxraw[2 * t] : idxraw[t];
    if (l < 0 || l >= NLORA) l = -1;
    if ((tid & 1) == 0) *(int*)(smem + 81920 + t_l * 4) = l;
    float4 s0 = make_float4(0.f, 0.f, 0.f, 0.f), s1 = s0;
    if (l >= 0) {
      for (int s = 0; s < nks; ++s) {
        const float4* p = (const float4*)(axpart + ((size_t)s * NTOK + t) * 256 + l * 16 + h8);
        const float4 a = p[0], bq = p[1];
        s0.x += a.x; s0.y += a.y; s0.z += a.z; s0.w += a.w;
        s1.x += bq.x; s1.y += bq.y; s1.z += bq.z; s1.w += bq.w;
      }
    }
    float4* d = (float4*)(smem + 65536 + t_l * 64 + h8 * 4);
    d[0] = s0; d[1] = s1;
  }
  // bias (global, tiny)
  float bv[4];
  #pragma unroll
  for (int j = 0; j < 4; ++j) {
    const int o = o0 + wc + j * 16 + c;
    bv[j] = isb ? b2f(((const unsigned short*)bias_raw)[o]) : ((const float*)bias_raw)[o];
  }
  // ---- two 8-lora halves of B (256 o-cols) cached in LDS as bf16 ----
  const int ol_ld = tid >> 1, rq = (tid & 1) * 8;   // o-col 0..255, rank octet
  #pragma unroll
  for (int h = 0; h < 2; ++h) {
    __syncthreads();
    #pragma unroll
    for (int lh = 0; lh < 8; ++lh) {
      const int l = h * 8 + lh;
      const size_t eoff = ((size_t)l * NOUT + o0 + ol_ld) * RANK + rq;
      uint4 pv;
      if (isb) {
        pv = *(const uint4*)((const unsigned short*)lorab_raw + eoff);
      } else {
        const float4* fp = (const float4*)((const float*)lorab_raw + eoff);
        const float4 v0 = fp[0], v1 = fp[1];
        pv.x = pk2(v0.x, v0.y); pv.y = pk2(v0.z, v0.w);
        pv.z = pk2(v1.x, v1.y); pv.w = pk2(v1.z, v1.w);
      }
      *(uint4*)(smem + lh * 8192 + ol_ld * 32 + rq * 2) = pv;
    }
    __syncthreads();
    #pragma unroll
    for (int mi = 0; mi < 8; ++mi) {
      #pragma unroll
      for (int r = 0; r < 4; ++r) {
        const int tl = wr + mi * 16 + rr + r;
        const int l = *(const int*)(smem + 81920 + tl * 4);
        if (l < 0 || (l >> 3) != h) continue;
        float axr[16];
        {
          const float4* ap = (const float4*)(smem + 65536 + tl * 64);
          #pragma unroll
          for (int g = 0; g < 4; ++g) {
            const float4 q = ap[g];
            axr[4 * g] = q.x; axr[4 * g + 1] = q.y;
            axr[4 * g + 2] = q.z; axr[4 * g + 3] = q.w;
          }
        }
        #pragma unroll
        for (int j = 0; j < 4; ++j) {
          const int ol = wc + j * 16 + c;
          const uint4 q0 = *(const uint4*)(smem + (l & 7) * 8192 + ol * 32);
          const uint4 q1 = *(const uint4*)(smem + (l & 7) * 8192 + ol * 32 + 16);
          float d = 0.f;
          const unsigned int qa[8] = {q0.x, q0.y, q0.z, q0.w, q1.x, q1.y, q1.z, q1.w};
          #pragma unroll
          for (int g = 0; g < 8; ++g) {
            d += b2f((unsigned short)(qa[g] & 0xFFFF)) * axr[2 * g];
            d += b2f((unsigned short)(qa[g] >> 16)) * axr[2 * g + 1];
          }
          acc[mi][j][r] += d;
        }
      }
    }
  }
  // ---- store output ----
  unsigned short* outb = (unsigned short*)outv;
  float* outf = (float*)outv;
  #pragma unroll
  for (int mi = 0; mi < 8; ++mi) {
    #pragma unroll
    for (int r = 0; r < 4; ++r) {
      const size_t t = t0 + wr + mi * 16 + rr + r;
      #pragma unroll
      for (int j = 0; j < 4; ++j) {
        const int o = o0 + wc + j * 16 + c;
        const float v = acc[mi][j][r] + bv[j];
        const size_t oi = t * NOUT + o;
        if (isb) outb[oi] = f2b(v); else outf[oi] = v;
      }
    }
  }
}

// ============ fallback main GEMM (R1-exact, 103.8 us proven) =================
__global__ __launch_bounds__(512, 2) void gemm_kernel(
    const void* __restrict__ x_raw, const void* __restrict__ w_raw,
    const unsigned short* __restrict__ xb_ws, const unsigned short* __restrict__ wb_ws,
    const void* __restrict__ bias_raw, const void* __restrict__ lorab_raw,
    const float* __restrict__ axpart, const int* __restrict__ idxraw,
    int nks, void* __restrict__ outv) {
  __shared__ char smem[98304];
  const int isb = detect_bf16(x_raw);
  const int i64 = detect_i64(idxraw);
  const unsigned short* Xb = isb ? (const unsigned short*)x_raw : xb_ws;
  const unsigned short* Wb = isb ? (const unsigned short*)w_raw : wb_ws;

  const int tid = threadIdx.x;
  const int wave = tid >> 6;
  const int lane = tid & 63;
  const int id = blockIdx.x;
  const int xcd = id & 7, slot = id >> 3;
  const int o0 = (xcd * 4 + (slot & 3)) * 128;
  const int t0 = (slot >> 2) * 256;
  const int wr = (wave >> 1) * 64;
  const int wc = (wave & 1) * 64;

  const int q_ = ((lane & 3) ^ ((lane >> 3) & 3)) * 16;
  const int srw = (lane >> 2);
  const char* gA0 = (const char*)Xb + (size_t)(t0 + 0 + wave * 16 + srw) * (HID * 2) + q_;
  const char* gA1 = (const char*)Xb + (size_t)(t0 + 128 + wave * 16 + srw) * (HID * 2) + q_;
  const char* gB0 = (const char*)Wb + (size_t)(o0 + wave * 16 + srw) * (HID * 2) + q_;

  const int fm = lane & 15, fq = lane >> 4;
  const int sw2 = (fm >> 1) & 3;
  int aOff[4], bOff[4];
  #pragma unroll
  for (int i = 0; i < 4; ++i) {
    aOff[i] = (wr + i * 16 + fm) * 64 + ((fq ^ sw2) << 4);
    bOff[i] = 16384 + (wc + i * 16 + fm) * 64 + ((fq ^ sw2) << 4);
  }
  floatx4 acc[4][4];
  #pragma unroll
  for (int i = 0; i < 4; ++i)
    #pragma unroll
    for (int j = 0; j < 4; ++j) acc[i][j] = (floatx4){0.f, 0.f, 0.f, 0.f};

#define STAGE(K, B) do {                                  \
    const size_t kb_ = (size_t)(K) * 64;                  \
    char* d_ = smem + (B) * 24576 + wave * 1024;          \
    gld16(gA0 + kb_, d_);                                 \
    gld16(gA1 + kb_, d_ + 8192);                          \
    gld16(gB0 + kb_, d_ + 16384);                         \
  } while (0)

#define COMPUTE(B) do {                                                         \
    const char* base_ = smem + (B) * 24576;                                     \
    bf16x8 af[4], bfv[4];                                                       \
    _Pragma("unroll")                                                           \
    for (int i = 0; i < 4; ++i) af[i] = *(const bf16x8*)(base_ + aOff[i]);      \
    _Pragma("unroll")                                                           \
    for (int j = 0; j < 4; ++j) bfv[j] = *(const bf16x8*)(base_ + bOff[j]);     \
    __builtin_amdgcn_s_setprio(1);                                              \
    _Pragma("unroll")                                                           \
    for (int i = 0; i < 4; ++i)                                                 \
      _Pragma("unroll")                                                         \
      for (int j = 0; j < 4; ++j)                                               \
        acc[i][j] = __builtin_amdgcn_mfma_f32_16x16x32_bf16(af[i], bfv[j], acc[i][j], 0, 0, 0); \
    __builtin_amdgcn_s_setprio(0);                                              \
  } while (0)

  const int KITER = HID / 32;
  STAGE(0, 0);
  STAGE(1, 1);
  STAGE(2, 2);
  for (int k = 0; k < KITER - 3; ++k) {
    asm volatile("s_waitcnt vmcnt(6)" ::: "memory");
    __builtin_amdgcn_s_barrier();
    STAGE(k + 3, (k + 3) & 3);
    COMPUTE(k & 3);
  }
  asm volatile("s_waitcnt vmcnt(6)" ::: "memory");
  __builtin_amdgcn_s_barrier();
  COMPUTE((KITER - 3) & 3);
  asm volatile("s_waitcnt vmcnt(3)" ::: "memory");
  __builtin_amdgcn_s_barrier();
  COMPUTE((KITER - 2) & 3);
  asm volatile("s_waitcnt vmcnt(0)" ::: "memory");
  __builtin_amdgcn_s_barrier();
  COMPUTE((KITER - 1) & 3);
#undef STAGE
#undef COMPUTE
  __syncthreads();

  {
    const int t_l = tid >> 1, h8 = (tid & 1) * 8;
    const int t = t0 + t_l;
    int l = i64 ? idxraw[2 * t] : idxraw[t];
    if (l < 0 || l >= NLORA) l = -1;
    if ((tid & 1) == 0) *(int*)(smem + 49152 + t_l * 4) = l;
    float4 s0 = make_float4(0.f, 0.f, 0.f, 0.f), s1 = s0;
    if (l >= 0) {
      for (int s = 0; s < nks; ++s) {
        const float4* p = (const float4*)(axpart + ((size_t)s * NTOK + t) * 256 + l * 16 + h8);
        const float4 a = p[0], bq = p[1];
        s0.x += a.x; s0.y += a.y; s0.z += a.z; s0.w += a.w;
        s1.x += bq.x; s1.y += bq.y; s1.z += bq.z; s1.w += bq.w;
      }
    }
    float4* d = (float4*)(smem + 32768 + t_l * 64 + h8 * 4);
    d[0] = s0; d[1] = s1;
  }
  const int c = lane & 15;
  const int rr = (lane >> 4) * 4;
  float bv[4];
  #pragma unroll
  for (int j = 0; j < 4; ++j) {
    const int o = o0 + wc + j * 16 + c;
    bv[j] = isb ? b2f(((const unsigned short*)bias_raw)[o]) : ((const float*)bias_raw)[o];
  }
  const int ol_ld = tid >> 2, rq = (tid & 3) * 4;
  #pragma unroll
  for (int h = 0; h < 2; ++h) {
    __syncthreads();
    #pragma unroll
    for (int lh = 0; lh < 8; ++lh) {
      const int l = h * 8 + lh;
      const size_t eoff = ((size_t)l * NOUT + o0 + ol_ld) * RANK + rq;
      uint2 pv;
      if (isb) {
        pv = *(const uint2*)((const unsigned short*)lorab_raw + eoff);
      } else {
        const float4 v = *(const float4*)((const float*)lorab_raw + eoff);
        pv.x = pk2(v.x, v.y); pv.y = pk2(v.z, v.w);
      }
      *(uint2*)(smem + lh * 4096 + ol_ld * 32 + rq * 2) = pv;
    }
    __syncthreads();
    #pragma unroll
    for (int mi = 0; mi < 4; ++mi) {
      #pragma unroll
      for (int r = 0; r < 4; ++r) {
        const int tl = wr + mi * 16 + rr + r;
        const int l = *(const int*)(smem + 49152 + tl * 4);
        if (l < 0 || (l >> 3) != h) continue;
        float axr[16];
        {
          const float4* ap = (const float4*)(smem + 32768 + tl * 64);
          #pragma unroll
          for (int g = 0; g < 4; ++g) {
            const float4 q = ap[g];
            axr[4 * g] = q.x; axr[4 * g + 1] = q.y;
            axr[4 * g + 2] = q.z; axr[4 * g + 3] = q.w;
          }
        }
        #pragma unroll
        for (int j = 0; j < 4; ++j) {
          const int ol = wc + j * 16 + c;
          const uint4 q0 = *(const uint4*)(smem + (l & 7) * 4096 + ol * 32);
          const uint4 q1 = *(const uint4*)(smem + (l & 7) * 4096 + ol * 32 + 16);
          float d = 0.f;
          const unsigned int qa[8] = {q0.x, q0.y, q0.z, q0.w, q1.x, q1.y, q1.z, q1.w};
          #pragma unroll
          for (int g = 0; g < 8; ++g) {
            d += b2f((unsigned short)(qa[g] & 0xFFFF)) * axr[2 * g];
            d += b2f((unsigned short)(qa[g] >> 16)) * axr[2 * g + 1];
          }
          acc[mi][j][r] += d;
        }
      }
    }
  }
  unsigned short* outb = (unsigned short*)outv;
  float* outf = (float*)outv;
  #pragma unroll
  for (int mi = 0; mi < 4; ++mi) {
    #pragma unroll
    for (int r = 0; r < 4; ++r) {
      const size_t t = t0 + wr + mi * 16 + rr + r;
      #pragma unroll
      for (int j = 0; j < 4; ++j) {
        const int o = o0 + wc + j * 16 + c;
        const float v = acc[mi][j][r] + bv[j];
        const size_t oi = t * NOUT + o;
        if (isb) outb[oi] = f2b(v); else outf[oi] = v;
      }
    }
  }
}

extern "C" void kernel_launch(void* const* d_in, const int* in_sizes, int n_in,
                              void* d_out, int out_size, void* d_ws, size_t ws_size,
                              hipStream_t stream) {
  const void* x  = d_in[0];
  const void* w  = d_in[1];
  const void* bs = d_in[2];
  const void* la = d_in[3];
  const void* lb = d_in[4];
  const int*  ix = (const int*)d_in[5];

  const size_t xb_bytes = (size_t)NTOK * HID * 2;
  const size_t wb_bytes = (size_t)NOUT * HID * 2;
  const size_t ax1      = (size_t)NTOK * 256 * 4;          // one k-slice
  const size_t P_bytes  = (size_t)2 * NTOK * NOUT * 4;     // K-split partials
  const size_t cnt_bytes = 512;                            // 128 tile counters

  char* ws = (char*)d_ws;

  if (ws_size >= xb_bytes + wb_bytes + 8 * ax1 + P_bytes + cnt_bytes + 64) {
    // K-split path: full-chip 256x256 tiles, last-block-fused reduce+epilogue.
    unsigned short* xb  = (unsigned short*)ws;
    unsigned short* wb2 = (unsigned short*)(ws + xb_bytes);
    float* axp = (float*)(ws + xb_bytes + wb_bytes);
    float* P   = (float*)(ws + xb_bytes + wb_bytes + 8 * ax1);
    int*   cnt = (int*)(ws + xb_bytes + wb_bytes + 8 * ax1 + P_bytes);
    prep_kernel<<<32 * 8 + 2048, 256, 0, stream>>>(x, w, la, xb, wb2, axp, 8, 1, cnt);
    gemm_ks2_kernel<<<256, 512, 0, stream>>>(x, w, xb, wb2, bs, lb, axp, ix, 8, P, cnt, d_out);
    return;
  }

  // fallback ladder (R1-exact path)
  int nks, full;
  unsigned short *xb, *wb2;
  float* axp;
  if (ws_size >= xb_bytes + wb_bytes + 8 * ax1 + 64) {
    nks = 8; full = 1;
    xb = (unsigned short*)ws;
    wb2 = (unsigned short*)(ws + xb_bytes);
    axp = (float*)(ws + xb_bytes + wb_bytes);
  } else if (ws_size >= xb_bytes + wb_bytes + 2 * ax1 + 64) {
    nks = 2; full = 1;
    xb = (unsigned short*)ws;
    wb2 = (unsigned short*)(ws + xb_bytes);
    axp = (float*)(ws + xb_bytes + wb_bytes);
  } else {
    nks = 2; full = 0;
    xb = (unsigned short*)x;
    wb2 = (unsigned short*)w;
    axp = (float*)ws;
  }

  prep_kernel<<<32 * nks + 2048, 256, 0, stream>>>(
      x, w, la, xb, wb2, axp, nks, full, (int*)0);
  gemm_kernel<<<256, 512, 0, stream>>>(
      x, w, xb, wb2, bs, lb, axp, ix, nks, d_out);
}

// Round 6
// 276.314 us; speedup vs baseline: 1.4911x; 1.4911x over previous
//
#include <hip/hip_runtime.h>

#define NTOK 2048
#define HID 4096
#define NOUT 4096
#define NLORA 16
#define RANK 16

typedef float floatx4 __attribute__((ext_vector_type(4)));
typedef __bf16 bf16x8 __attribute__((ext_vector_type(8)));

__device__ __forceinline__ unsigned short f2b(float f) {
  unsigned int u = __float_as_uint(f);
  u += 0x7FFFu + ((u >> 16) & 1u);   // round-to-nearest-even
  return (unsigned short)(u >> 16);
}
__device__ __forceinline__ float b2f(unsigned short u) {
  return __uint_as_float(((unsigned int)u) << 16);
}
__device__ __forceinline__ unsigned int pk2(float a, float b) {
  return (unsigned int)f2b(a) | ((unsigned int)f2b(b) << 16);
}

// async global->LDS, 16 B/lane; LDS dest is wave-uniform base (+ lane*16 in HW)
__device__ __forceinline__ void gld16(const char* g, char* l) {
  __builtin_amdgcn_global_load_lds(
      (const __attribute__((address_space(1))) unsigned int*)g,
      (__attribute__((address_space(3))) unsigned int*)l,
      16, 0, 0);
}

// ---- inline per-wave dtype detection ----
__device__ __forceinline__ int detect_bf16(const void* xraw) {
  const int lane = threadIdx.x & 63;
  const int e = (((const unsigned short*)xraw)[2 * lane] >> 7) & 0xFF;
  const unsigned long long wild = __ballot(e < 96 || e > 159);
  return wild == 0ull;
}
__device__ __forceinline__ int detect_i64(const int* idxraw) {
  const int lane = threadIdx.x & 63;
  const unsigned long long nz = __ballot((lane & 1) && idxraw[lane] != 0);
  return nz == 0ull;
}

// ============ prep: axall slices (+X conversion side-effect) + W conversion ==
// (R4-verbatim; no counters, no fences)
__global__ __launch_bounds__(256) void prep_kernel(
    const void* __restrict__ xv, const void* __restrict__ wv,
    const void* __restrict__ lav,
    unsigned short* __restrict__ xb, unsigned short* __restrict__ wb,
    float* __restrict__ axpart, int nks, int full) {
  const int tid = threadIdx.x;
  const int isb = detect_bf16(xv);
  const int AXB = 32 * nks;
  if (blockIdx.x >= AXB) {
    if (isb || !full) return;
    const int W8 = NOUT * HID / 8;
    const int cb = blockIdx.x - AXB;
    for (int i = cb * 256 + tid; i < W8; i += 2048 * 256) {
      const float4 a = ((const float4*)wv)[2 * i];
      const float4 b = ((const float4*)wv)[2 * i + 1];
      uint4 p;
      p.x = pk2(a.x, a.y); p.y = pk2(a.z, a.w);
      p.z = pk2(b.x, b.y); p.w = pk2(b.z, b.w);
      ((uint4*)wb)[i] = p;
    }
    return;
  }
  __shared__ char sm[16384];           // X 8KB @0, Acat 8KB @8192 (64B rows)
  const int b = blockIdx.x;
  const int tt = b & 15, nt = (b >> 4) & 1, ks = b >> 5;
  const int t0 = tt * 128, n0 = nt * 128;
  const int kslice = HID / nks;
  const int k0 = ks * kslice;
  const int wave = tid >> 6, lane = tid & 63;
  const int isx = tid < 128;
  const int row = isx ? tid : tid - 128;
  const size_t gbase = (size_t)((isx ? t0 : n0) + row) * HID + k0;
  const float* srcF = (isx ? (const float*)xv : (const float*)lav) + gbase;
  const unsigned short* srcB =
      (isx ? (const unsigned short*)xv : (const unsigned short*)lav) + gbase;
  char* ldsrow = sm + (isx ? 0 : 8192) + row * 64;
  const int prm = (tid >> 1) & 3;      // (row>>1)&3
  const int wrxb = (isx && nt == 0 && !isb && full);
  unsigned short* xbrow = xb + (size_t)(t0 + row) * HID + k0;

  const int wr = (wave >> 1) * 64, wc = (wave & 1) * 64;
  const int fm = lane & 15, fq = lane >> 4;
  const int sw2 = (fm >> 1) & 3;
  int aO[4], bO[4];
  #pragma unroll
  for (int i = 0; i < 4; ++i) {
    aO[i] = (wr + i * 16 + fm) * 64 + ((fq ^ sw2) << 4);
    bO[i] = 8192 + (wc + i * 16 + fm) * 64 + ((fq ^ sw2) << 4);
  }
  floatx4 acc[4][4];
  #pragma unroll
  for (int i = 0; i < 4; ++i)
    #pragma unroll
    for (int j = 0; j < 4; ++j) acc[i][j] = (floatx4){0.f, 0.f, 0.f, 0.f};

  const int NIT = kslice / 32;
  for (int it = 0; it < NIT; ++it) {
    uint4 w[4];
    if (isb) {
      const uint4* s4 = (const uint4*)(srcB + it * 32);
      #pragma unroll
      for (int g = 0; g < 4; ++g) w[g] = s4[g];
    } else {
      const float4* s4 = (const float4*)(srcF + it * 32);
      #pragma unroll
      for (int g = 0; g < 4; ++g) {
        const float4 f0 = s4[2 * g], f1 = s4[2 * g + 1];
        w[g].x = pk2(f0.x, f0.y); w[g].y = pk2(f0.z, f0.w);
        w[g].z = pk2(f1.x, f1.y); w[g].w = pk2(f1.z, f1.w);
      }
      if (wrxb) {
        uint4* d = (uint4*)(xbrow + it * 32);
        #pragma unroll
        for (int g = 0; g < 4; ++g) d[g] = w[g];
      }
    }
    #pragma unroll
    for (int g = 0; g < 4; ++g)
      *(uint4*)(ldsrow + ((g ^ prm) << 4)) = w[g];
    __syncthreads();
    bf16x8 af[4], bfv[4];
    #pragma unroll
    for (int i = 0; i < 4; ++i) af[i] = *(const bf16x8*)(sm + aO[i]);
    #pragma unroll
    for (int j = 0; j < 4; ++j) bfv[j] = *(const bf16x8*)(sm + bO[j]);
    #pragma unroll
    for (int i = 0; i < 4; ++i)
      #pragma unroll
      for (int j = 0; j < 4; ++j)
        acc[i][j] = __builtin_amdgcn_mfma_f32_16x16x32_bf16(af[i], bfv[j], acc[i][j], 0, 0, 0);
    __syncthreads();
  }
  const int c = lane & 15, rr = (lane >> 4) * 4;
  #pragma unroll
  for (int i = 0; i < 4; ++i)
    #pragma unroll
    for (int r = 0; r < 4; ++r) {
      const int t = t0 + wr + i * 16 + rr + r;
      float* dst = axpart + ((size_t)ks * NTOK + t) * 256 + n0 + wc;
      #pragma unroll
      for (int j = 0; j < 4; ++j) dst[j * 16 + c] = acc[i][j][r];
    }
}

// ============ K-SPLIT main GEMM (R4-verbatim, 69 us proven) ==================
// 256x256 tile, half-K per block, 8 waves of 128x64, depth-2 counted vmcnt,
// 3x32KB LDS buffers, 0 bank conflicts. Writes f32 partials P[kh][t][o].
// No fences, no atomics: the kernel boundary is the split-K fence.
__global__ __launch_bounds__(512, 2) void gemm_ks_kernel(
    const void* __restrict__ x_raw, const void* __restrict__ w_raw,
    const unsigned short* __restrict__ xb_ws, const unsigned short* __restrict__ wb_ws,
    float* __restrict__ P) {
  __shared__ char smem[98304];  // buf b @ b*32768: A 16K @0, B 16K @16384
  const int isb = detect_bf16(x_raw);
  const unsigned short* Xb = isb ? (const unsigned short*)x_raw : xb_ws;
  const unsigned short* Wb = isb ? (const unsigned short*)w_raw : wb_ws;

  const int tid = threadIdx.x;
  const int wave = tid >> 6;
  const int lane = tid & 63;
  // XCD-compact: slot bits [0]=o, [3:1]=t, [4]=kh; per XCD: 2 o-tiles (W slab
  // 4MB = L2), 8 t-tiles, 2 K-halves.
  const int id = blockIdx.x;
  const int xcd = id & 7, slot = id >> 3;           // 0..31
  const int o0 = (xcd * 2 + (slot & 1)) * 256;
  const int t0 = ((slot >> 1) & 7) * 256;
  const int kh = slot >> 4;                          // 0..1
  const int wr = (wave >> 2) * 128;   // 2 row-groups of 128
  const int wc = (wave & 3) * 64;     // 4 col-groups of 64

  const int q_ = ((lane & 3) ^ ((lane >> 3) & 3)) * 16;
  const int srw = (lane >> 2);
  const char* gA = (const char*)Xb + (size_t)(t0 + wave * 32 + srw) * (HID * 2)
                 + q_ + (size_t)kh * 4096;
  const char* gB = (const char*)Wb + (size_t)(o0 + wave * 32 + srw) * (HID * 2)
                 + q_ + (size_t)kh * 4096;

  const int fm = lane & 15, fq = lane >> 4;
  const int sw2 = (fm >> 1) & 3;
  int aOff[8], bOff[4];
  #pragma unroll
  for (int i = 0; i < 8; ++i)
    aOff[i] = (wr + i * 16 + fm) * 64 + ((fq ^ sw2) << 4);
  #pragma unroll
  for (int j = 0; j < 4; ++j)
    bOff[j] = 16384 + (wc + j * 16 + fm) * 64 + ((fq ^ sw2) << 4);
  floatx4 acc[8][4];
  #pragma unroll
  for (int i = 0; i < 8; ++i)
    #pragma unroll
    for (int j = 0; j < 4; ++j) acc[i][j] = (floatx4){0.f, 0.f, 0.f, 0.f};

#define KSTAGE(K, B) do {                                         \
    const size_t kb_ = (size_t)(K) * 64;                          \
    char* d_ = smem + (B) * 32768 + wave * 2048;                  \
    gld16(gA + kb_,                           d_);                \
    gld16(gA + kb_ + 16 * (size_t)HID * 2,    d_ + 1024);         \
    gld16(gB + kb_,                           d_ + 16384);        \
    gld16(gB + kb_ + 16 * (size_t)HID * 2,    d_ + 17408);       \
  } while (0)

#define KCOMPUTE(B) do {                                                        \
    const char* base_ = smem + (B) * 32768;                                     \
    bf16x8 af[8], bfv[4];                                                       \
    _Pragma("unroll")                                                           \
    for (int i = 0; i < 8; ++i) af[i] = *(const bf16x8*)(base_ + aOff[i]);      \
    _Pragma("unroll")                                                           \
    for (int j = 0; j < 4; ++j) bfv[j] = *(const bf16x8*)(base_ + bOff[j]);     \
    _Pragma("unroll")                                                           \
    for (int i = 0; i < 8; ++i)                                                 \
      _Pragma("unroll")                                                         \
      for (int j = 0; j < 4; ++j)                                               \
        acc[i][j] = __builtin_amdgcn_mfma_f32_16x16x32_bf16(af[i], bfv[j], acc[i][j], 0, 0, 0); \
  } while (0)

  const int KITER = (HID / 2) / 32;   // 64 K-steps per half
  int cb = 0, sb = 2;
  KSTAGE(0, 0);
  KSTAGE(1, 1);
  for (int k = 0; k < KITER - 2; ++k) {
    asm volatile("s_waitcnt vmcnt(4)" ::: "memory");
    __builtin_amdgcn_s_barrier();
    KSTAGE(k + 2, sb);
    KCOMPUTE(cb);
    cb = (cb == 2) ? 0 : cb + 1;
    sb = (sb == 2) ? 0 : sb + 1;
  }
  asm volatile("s_waitcnt vmcnt(4)" ::: "memory");
  __builtin_amdgcn_s_barrier();
  KCOMPUTE(cb);
  cb = (cb == 2) ? 0 : cb + 1;
  asm volatile("s_waitcnt vmcnt(0)" ::: "memory");
  __builtin_amdgcn_s_barrier();
  KCOMPUTE(cb);
#undef KSTAGE
#undef KCOMPUTE

  // ---- store f32 partial tile ----
  const int c = lane & 15, rr = (lane >> 4) * 4;
  #pragma unroll
  for (int mi = 0; mi < 8; ++mi) {
    #pragma unroll
    for (int r = 0; r < 4; ++r) {
      const size_t t = t0 + wr + mi * 16 + rr + r;
      float* dst = P + ((size_t)kh * NTOK + t) * NOUT + o0 + wc;
      #pragma unroll
      for (int j = 0; j < 4; ++j) dst[j * 16 + c] = acc[mi][j][r];
    }
  }
}

// ============ reduce2: coalesced P0+P1 fold + bias + LoRA epilogue ===========
// Tile 256t x 128o per block (grid 256). Thread owns an 8-row x 8-col patch:
// rows t0 + (tid>>4)*8 + rr, cols o0 + (tid&15)*8. Every P load / out store
// is a 512B-contiguous wave segment (vs the old fragment-layout 64B segments
// that held the R4 reduce at 1.8 TB/s).
// lora_B cached in LDS as rank-pair words: word(l,rp,col) @ (l&7)*4096 +
// rp*512 + col*4 holds bf16(r=2rp) | bf16(r=2rp+1)<<16. Reader uint4 spans
// 4 cols at one rp -> <=2-way bank aliasing.
__global__ __launch_bounds__(512) void reduce2_kernel(
    const void* __restrict__ x_raw, const float* __restrict__ P,
    const void* __restrict__ bias_raw, const void* __restrict__ lorab_raw,
    const float* __restrict__ axpart, const int* __restrict__ idxraw,
    int nks, void* __restrict__ outv) {
  __shared__ char smem[50176];  // Bl 32K @0, axs 16K @32768, tok 1K @49152
  const int isb = detect_bf16(x_raw);
  const int i64 = detect_i64(idxraw);
  const int tid = threadIdx.x;
  const int id = blockIdx.x;
  const int xcd = id & 7, slot = id >> 3;
  const int o0 = (xcd * 4 + (slot & 3)) * 128;
  const int t0 = (slot >> 2) * 256;
  const int cix = tid & 15;          // col octet: cols o0+cix*8 .. +7
  const int rix = tid >> 4;          // row octet group 0..31

  // ---- phase a: tok + slice-summed ax tables in LDS (proven R4 code) ----
  {
    const int t_l = tid >> 1, h8 = (tid & 1) * 8;
    const int t = t0 + t_l;
    int l = i64 ? idxraw[2 * t] : idxraw[t];
    if (l < 0 || l >= NLORA) l = -1;
    if ((tid & 1) == 0) *(int*)(smem + 49152 + t_l * 4) = l;
    float4 s0 = make_float4(0.f, 0.f, 0.f, 0.f), s1 = s0;
    if (l >= 0) {
      for (int s = 0; s < nks; ++s) {
        const float4* p = (const float4*)(axpart + ((size_t)s * NTOK + t) * 256 + l * 16 + h8);
        const float4 a = p[0], bq = p[1];
        s0.x += a.x; s0.y += a.y; s0.z += a.z; s0.w += a.w;
        s1.x += bq.x; s1.y += bq.y; s1.z += bq.z; s1.w += bq.w;
      }
    }
    float4* d = (float4*)(smem + 32768 + t_l * 64 + h8 * 4);
    d[0] = s0; d[1] = s1;
  }

  // ---- fold P0+P1 (coalesced) + bias into acc[8][8] ----
  float acc[8][8];
  float bv[8];
  const int ob = o0 + cix * 8;
  if (isb) {
    #pragma unroll
    for (int k = 0; k < 8; ++k) bv[k] = b2f(((const unsigned short*)bias_raw)[ob + k]);
  } else {
    const float4* bp = (const float4*)((const float*)bias_raw + ob);
    const float4 b0 = bp[0], b1 = bp[1];
    bv[0] = b0.x; bv[1] = b0.y; bv[2] = b0.z; bv[3] = b0.w;
    bv[4] = b1.x; bv[5] = b1.y; bv[6] = b1.z; bv[7] = b1.w;
  }
  #pragma unroll
  for (int rr = 0; rr < 8; ++rr) {
    const size_t row = t0 + rix * 8 + rr;
    const float4* p0 = (const float4*)(P + row * NOUT + ob);
    const float4* p1 = (const float4*)(P + ((size_t)NTOK + row) * NOUT + ob);
    const float4 a0 = p0[0], a1 = p0[1], c0 = p1[0], c1 = p1[1];
    acc[rr][0] = a0.x + c0.x; acc[rr][1] = a0.y + c0.y;
    acc[rr][2] = a0.z + c0.z; acc[rr][3] = a0.w + c0.w;
    acc[rr][4] = a1.x + c1.x; acc[rr][5] = a1.y + c1.y;
    acc[rr][6] = a1.z + c1.z; acc[rr][7] = a1.w + c1.w;
  }

  // ---- two 8-lora halves: load Bl words, apply deltas ----
  const int lcol = tid & 127;        // loader col 0..127
  const int lrh = tid >> 7;          // loader rank-quad 0..3 -> rp = lrh*2, +1
  #pragma unroll
  for (int h = 0; h < 2; ++h) {
    __syncthreads();
    #pragma unroll
    for (int lh = 0; lh < 8; ++lh) {
      const int l = h * 8 + lh;
      const size_t eoff = ((size_t)l * NOUT + o0 + lcol) * RANK + lrh * 4;
      uint2 pv;
      if (isb) {
        pv = *(const uint2*)((const unsigned short*)lorab_raw + eoff);
      } else {
        const float4 v = *(const float4*)((const float*)lorab_raw + eoff);
        pv.x = pk2(v.x, v.y); pv.y = pk2(v.z, v.w);
      }
      unsigned int* wp = (unsigned int*)(smem + lh * 4096 + (lrh * 2) * 512 + lcol * 4);
      wp[0] = pv.x;        // rp = lrh*2
      wp[128] = pv.y;      // rp = lrh*2+1 (+512B)
    }
    __syncthreads();
    #pragma unroll
    for (int rr = 0; rr < 8; ++rr) {
      const int l = *(const int*)(smem + 49152 + (rix * 8 + rr) * 4);
      if (l < 0 || (l >> 3) != h) continue;
      float axr[16];
      {
        const float4* ap = (const float4*)(smem + 32768 + (rix * 8 + rr) * 64);
        #pragma unroll
        for (int g = 0; g < 4; ++g) {
          const float4 q = ap[g];
          axr[4 * g] = q.x; axr[4 * g + 1] = q.y;
          axr[4 * g + 2] = q.z; axr[4 * g + 3] = q.w;
        }
      }
      const char* bb = smem + (l & 7) * 4096 + cix * 32;
      #pragma unroll
      for (int rp = 0; rp < 8; ++rp) {
        const uint4 q0 = *(const uint4*)(bb + rp * 512);
        const uint4 q1 = *(const uint4*)(bb + rp * 512 + 16);
        const float a0 = axr[2 * rp], a1 = axr[2 * rp + 1];
        const unsigned int qa[8] = {q0.x, q0.y, q0.z, q0.w, q1.x, q1.y, q1.z, q1.w};
        #pragma unroll
        for (int w = 0; w < 8; ++w) {
          acc[rr][w] += b2f((unsigned short)(qa[w] & 0xFFFF)) * a0
                      + b2f((unsigned short)(qa[w] >> 16)) * a1;
        }
      }
    }
  }

  // ---- store (coalesced) ----
  #pragma unroll
  for (int rr = 0; rr < 8; ++rr) {
    const size_t row = t0 + rix * 8 + rr;
    if (isb) {
      unsigned short* ob16 = (unsigned short*)outv + row * NOUT + ob;
      uint4 pv;
      pv.x = pk2(acc[rr][0] + bv[0], acc[rr][1] + bv[1]);
      pv.y = pk2(acc[rr][2] + bv[2], acc[rr][3] + bv[3]);
      pv.z = pk2(acc[rr][4] + bv[4], acc[rr][5] + bv[5]);
      pv.w = pk2(acc[rr][6] + bv[6], acc[rr][7] + bv[7]);
      *(uint4*)ob16 = pv;
    } else {
      float4* of = (float4*)((float*)outv + row * NOUT + ob);
      of[0] = make_float4(acc[rr][0] + bv[0], acc[rr][1] + bv[1],
                          acc[rr][2] + bv[2], acc[rr][3] + bv[3]);
      of[1] = make_float4(acc[rr][4] + bv[4], acc[rr][5] + bv[5],
                          acc[rr][6] + bv[6], acc[rr][7] + bv[7]);
    }
  }
}

// ============ fallback main GEMM (R1-exact, 103.8 us proven) =================
__global__ __launch_bounds__(512, 2) void gemm_kernel(
    const void* __restrict__ x_raw, const void* __restrict__ w_raw,
    const unsigned short* __restrict__ xb_ws, const unsigned short* __restrict__ wb_ws,
    const void* __restrict__ bias_raw, const void* __restrict__ lorab_raw,
    const float* __restrict__ axpart, const int* __restrict__ idxraw,
    int nks, void* __restrict__ outv) {
  __shared__ char smem[98304];
  const int isb = detect_bf16(x_raw);
  const int i64 = detect_i64(idxraw);
  const unsigned short* Xb = isb ? (const unsigned short*)x_raw : xb_ws;
  const unsigned short* Wb = isb ? (const unsigned short*)w_raw : wb_ws;

  const int tid = threadIdx.x;
  const int wave = tid >> 6;
  const int lane = tid & 63;
  const int id = blockIdx.x;
  const int xcd = id & 7, slot = id >> 3;
  const int o0 = (xcd * 4 + (slot & 3)) * 128;
  const int t0 = (slot >> 2) * 256;
  const int wr = (wave >> 1) * 64;
  const int wc = (wave & 1) * 64;

  const int q_ = ((lane & 3) ^ ((lane >> 3) & 3)) * 16;
  const int srw = (lane >> 2);
  const char* gA0 = (const char*)Xb + (size_t)(t0 + 0 + wave * 16 + srw) * (HID * 2) + q_;
  const char* gA1 = (const char*)Xb + (size_t)(t0 + 128 + wave * 16 + srw) * (HID * 2) + q_;
  const char* gB0 = (const char*)Wb + (size_t)(o0 + wave * 16 + srw) * (HID * 2) + q_;

  const int fm = lane & 15, fq = lane >> 4;
  const int sw2 = (fm >> 1) & 3;
  int aOff[4], bOff[4];
  #pragma unroll
  for (int i = 0; i < 4; ++i) {
    aOff[i] = (wr + i * 16 + fm) * 64 + ((fq ^ sw2) << 4);
    bOff[i] = 16384 + (wc + i * 16 + fm) * 64 + ((fq ^ sw2) << 4);
  }
  floatx4 acc[4][4];
  #pragma unroll
  for (int i = 0; i < 4; ++i)
    #pragma unroll
    for (int j = 0; j < 4; ++j) acc[i][j] = (floatx4){0.f, 0.f, 0.f, 0.f};

#define STAGE(K, B) do {                                  \
    const size_t kb_ = (size_t)(K) * 64;                  \
    char* d_ = smem + (B) * 24576 + wave * 1024;          \
    gld16(gA0 + kb_, d_);                                 \
    gld16(gA1 + kb_, d_ + 8192);                          \
    gld16(gB0 + kb_, d_ + 16384);                         \
  } while (0)

#define COMPUTE(B) do {                                                         \
    const char* base_ = smem + (B) * 24576;                                     \
    bf16x8 af[4], bfv[4];                                                       \
    _Pragma("unroll")                                                           \
    for (int i = 0; i < 4; ++i) af[i] = *(const bf16x8*)(base_ + aOff[i]);      \
    _Pragma("unroll")                                                           \
    for (int j = 0; j < 4; ++j) bfv[j] = *(const bf16x8*)(base_ + bOff[j]);     \
    __builtin_amdgcn_s_setprio(1);                                              \
    _Pragma("unroll")                                                           \
    for (int i = 0; i < 4; ++i)                                                 \
      _Pragma("unroll")                                                         \
      for (int j = 0; j < 4; ++j)                                               \
        acc[i][j] = __builtin_amdgcn_mfma_f32_16x16x32_bf16(af[i], bfv[j], acc[i][j], 0, 0, 0); \
    __builtin_amdgcn_s_setprio(0);                                              \
  } while (0)

  const int KITER = HID / 32;
  STAGE(0, 0);
  STAGE(1, 1);
  STAGE(2, 2);
  for (int k = 0; k < KITER - 3; ++k) {
    asm volatile("s_waitcnt vmcnt(6)" ::: "memory");
    __builtin_amdgcn_s_barrier();
    STAGE(k + 3, (k + 3) & 3);
    COMPUTE(k & 3);
  }
  asm volatile("s_waitcnt vmcnt(6)" ::: "memory");
  __builtin_amdgcn_s_barrier();
  COMPUTE((KITER - 3) & 3);
  asm volatile("s_waitcnt vmcnt(3)" ::: "memory");
  __builtin_amdgcn_s_barrier();
  COMPUTE((KITER - 2) & 3);
  asm volatile("s_waitcnt vmcnt(0)" ::: "memory");
  __builtin_amdgcn_s_barrier();
  COMPUTE((KITER - 1) & 3);
#undef STAGE
#undef COMPUTE
  __syncthreads();

  {
    const int t_l = tid >> 1, h8 = (tid & 1) * 8;
    const int t = t0 + t_l;
    int l = i64 ? idxraw[2 * t] : idxraw[t];
    if (l < 0 || l >= NLORA) l = -1;
    if ((tid & 1) == 0) *(int*)(smem + 49152 + t_l * 4) = l;
    float4 s0 = make_float4(0.f, 0.f, 0.f, 0.f), s1 = s0;
    if (l >= 0) {
      for (int s = 0; s < nks; ++s) {
        const float4* p = (const float4*)(axpart + ((size_t)s * NTOK + t) * 256 + l * 16 + h8);
        const float4 a = p[0], bq = p[1];
        s0.x += a.x; s0.y += a.y; s0.z += a.z; s0.w += a.w;
        s1.x += bq.x; s1.y += bq.y; s1.z += bq.z; s1.w += bq.w;
      }
    }
    float4* d = (float4*)(smem + 32768 + t_l * 64 + h8 * 4);
    d[0] = s0; d[1] = s1;
  }
  const int c = lane & 15;
  const int rr = (lane >> 4) * 4;
  float bv[4];
  #pragma unroll
  for (int j = 0; j < 4; ++j) {
    const int o = o0 + wc + j * 16 + c;
    bv[j] = isb ? b2f(((const unsigned short*)bias_raw)[o]) : ((const float*)bias_raw)[o];
  }
  const int ol_ld = tid >> 2, rq = (tid & 3) * 4;
  #pragma unroll
  for (int h = 0; h < 2; ++h) {
    __syncthreads();
    #pragma unroll
    for (int lh = 0; lh < 8; ++lh) {
      const int l = h * 8 + lh;
      const size_t eoff = ((size_t)l * NOUT + o0 + ol_ld) * RANK + rq;
      uint2 pv;
      if (isb) {
        pv = *(const uint2*)((const unsigned short*)lorab_raw + eoff);
      } else {
        const float4 v = *(const float4*)((const float*)lorab_raw + eoff);
        pv.x = pk2(v.x, v.y); pv.y = pk2(v.z, v.w);
      }
      *(uint2*)(smem + lh * 4096 + ol_ld * 32 + rq * 2) = pv;
    }
    __syncthreads();
    #pragma unroll
    for (int mi = 0; mi < 4; ++mi) {
      #pragma unroll
      for (int r = 0; r < 4; ++r) {
        const int tl = wr + mi * 16 + rr + r;
        const int l = *(const int*)(smem + 49152 + tl * 4);
        if (l < 0 || (l >> 3) != h) continue;
        float axr[16];
        {
          const float4* ap = (const float4*)(smem + 32768 + tl * 64);
          #pragma unroll
          for (int g = 0; g < 4; ++g) {
            const float4 q = ap[g];
            axr[4 * g] = q.x; axr[4 * g + 1] = q.y;
            axr[4 * g + 2] = q.z; axr[4 * g + 3] = q.w;
          }
        }
        #pragma unroll
        for (int j = 0; j < 4; ++j) {
          const int ol = wc + j * 16 + c;
          const uint4 q0 = *(const uint4*)(smem + (l & 7) * 4096 + ol * 32);
          const uint4 q1 = *(const uint4*)(smem + (l & 7) * 4096 + ol * 32 + 16);
          float d = 0.f;
          const unsigned int qa[8] = {q0.x, q0.y, q0.z, q0.w, q1.x, q1.y, q1.z, q1.w};
          #pragma unroll
          for (int g = 0; g < 8; ++g) {
            d += b2f((unsigned short)(qa[g] & 0xFFFF)) * axr[2 * g];
            d += b2f((unsigned short)(qa[g] >> 16)) * axr[2 * g + 1];
          }
          acc[mi][j][r] += d;
        }
      }
    }
  }
  unsigned short* outb = (unsigned short*)outv;
  float* outf = (float*)outv;
  #pragma unroll
  for (int mi = 0; mi < 4; ++mi) {
    #pragma unroll
    for (int r = 0; r < 4; ++r) {
      const size_t t = t0 + wr + mi * 16 + rr + r;
      #pragma unroll
      for (int j = 0; j < 4; ++j) {
        const int o = o0 + wc + j * 16 + c;
        const float v = acc[mi][j][r] + bv[j];
        const size_t oi = t * NOUT + o;
        if (isb) outb[oi] = f2b(v); else outf[oi] = v;
      }
    }
  }
}

extern "C" void kernel_launch(void* const* d_in, const int* in_sizes, int n_in,
                              void* d_out, int out_size, void* d_ws, size_t ws_size,
                              hipStream_t stream) {
  const void* x  = d_in[0];
  const void* w  = d_in[1];
  const void* bs = d_in[2];
  const void* la = d_in[3];
  const void* lb = d_in[4];
  const int*  ix = (const int*)d_in[5];

  const size_t xb_bytes = (size_t)NTOK * HID * 2;
  const size_t wb_bytes = (size_t)NOUT * HID * 2;
  const size_t ax1      = (size_t)NTOK * 256 * 4;          // one k-slice
  const size_t P_bytes  = (size_t)2 * NTOK * NOUT * 4;     // K-split partials

  char* ws = (char*)d_ws;

  if (ws_size >= xb_bytes + wb_bytes + 8 * ax1 + P_bytes + 64) {
    // K-split path: full-chip 256x256 tiles + coalesced reduce2 epilogue.
    unsigned short* xb  = (unsigned short*)ws;
    unsigned short* wb2 = (unsigned short*)(ws + xb_bytes);
    float* axp = (float*)(ws + xb_bytes + wb_bytes);
    float* P   = (float*)(ws + xb_bytes + wb_bytes + 8 * ax1);
    prep_kernel<<<32 * 8 + 2048, 256, 0, stream>>>(x, w, la, xb, wb2, axp, 8, 1);
    gemm_ks_kernel<<<256, 512, 0, stream>>>(x, w, xb, wb2, P);
    reduce2_kernel<<<256, 512, 0, stream>>>(x, P, bs, lb, axp, ix, 8, d_out);
    return;
  }

  // fallback ladder (R1-exact path)
  int nks, full;
  unsigned short *xb, *wb2;
  float* axp;
  if (ws_size >= xb_bytes + wb_bytes + 8 * ax1 + 64) {
    nks = 8; full = 1;
    xb = (unsigned short*)ws;
    wb2 = (unsigned short*)(ws + xb_bytes);
    axp = (float*)(ws + xb_bytes + wb_bytes);
  } else if (ws_size >= xb_bytes + wb_bytes + 2 * ax1 + 64) {
    nks = 2; full = 1;
    xb = (unsigned short*)ws;
    wb2 = (unsigned short*)(ws + xb_bytes);
    axp = (float*)(ws + xb_bytes + wb_bytes);
  } else {
    nks = 2; full = 0;
    xb = (unsigned short*)x;
    wb2 = (unsigned short*)w;
    axp = (float*)ws;
  }

  prep_kernel<<<32 * nks + 2048, 256, 0, stream>>>(
      x, w, la, xb, wb2, axp, nks, full);
  gemm_kernel<<<256, 512, 0, stream>>>(
      x, w, xb, wb2, bs, lb, axp, ix, nks, d_out);
}

// Round 8
// 275.516 us; speedup vs baseline: 1.4954x; 1.0029x over previous
//
#include <hip/hip_runtime.h>

#define NTOK 2048
#define HID 4096
#define NOUT 4096
#define NLORA 16
#define RANK 16

typedef float floatx4 __attribute__((ext_vector_type(4)));
typedef __bf16 bf16x8 __attribute__((ext_vector_type(8)));
// native vector types for __builtin_nontemporal_* (HIP float4/uint4 are
// structs and are rejected by the builtin — R7 compile failure)
typedef float f32x4 __attribute__((ext_vector_type(4)));
typedef unsigned int u32x4 __attribute__((ext_vector_type(4)));

__device__ __forceinline__ unsigned short f2b(float f) {
  unsigned int u = __float_as_uint(f);
  u += 0x7FFFu + ((u >> 16) & 1u);   // round-to-nearest-even
  return (unsigned short)(u >> 16);
}
__device__ __forceinline__ float b2f(unsigned short u) {
  return __uint_as_float(((unsigned int)u) << 16);
}
__device__ __forceinline__ unsigned int pk2(float a, float b) {
  return (unsigned int)f2b(a) | ((unsigned int)f2b(b) << 16);
}

// async global->LDS, 16 B/lane; LDS dest is wave-uniform base (+ lane*16 in HW)
__device__ __forceinline__ void gld16(const char* g, char* l) {
  __builtin_amdgcn_global_load_lds(
      (const __attribute__((address_space(1))) unsigned int*)g,
      (__attribute__((address_space(3))) unsigned int*)l,
      16, 0, 0);
}

// ---- inline per-wave dtype detection ----
__device__ __forceinline__ int detect_bf16(const void* xraw) {
  const int lane = threadIdx.x & 63;
  const int e = (((const unsigned short*)xraw)[2 * lane] >> 7) & 0xFF;
  const unsigned long long wild = __ballot(e < 96 || e > 159);
  return wild == 0ull;
}
__device__ __forceinline__ int detect_i64(const int* idxraw) {
  const int lane = threadIdx.x & 63;
  const unsigned long long nz = __ballot((lane & 1) && idxraw[lane] != 0);
  return nz == 0ull;
}

// ============ prep: axall slices (+X conversion side-effect) + W conversion ==
// (unchanged except nt hints on the read-once W stream)
__global__ __launch_bounds__(256) void prep_kernel(
    const void* __restrict__ xv, const void* __restrict__ wv,
    const void* __restrict__ lav,
    unsigned short* __restrict__ xb, unsigned short* __restrict__ wb,
    float* __restrict__ axpart, int nks, int full) {
  const int tid = threadIdx.x;
  const int isb = detect_bf16(xv);
  const int AXB = 32 * nks;
  if (blockIdx.x >= AXB) {
    if (isb || !full) return;
    const int W8 = NOUT * HID / 8;
    const int cb = blockIdx.x - AXB;
    for (int i = cb * 256 + tid; i < W8; i += 2048 * 256) {
      const f32x4 a = __builtin_nontemporal_load((const f32x4*)wv + 2 * i);
      const f32x4 b = __builtin_nontemporal_load((const f32x4*)wv + 2 * i + 1);
      u32x4 p;
      p[0] = pk2(a[0], a[1]); p[1] = pk2(a[2], a[3]);
      p[2] = pk2(b[0], b[1]); p[3] = pk2(b[2], b[3]);
      __builtin_nontemporal_store(p, (u32x4*)wb + i);
    }
    return;
  }
  __shared__ char sm[16384];           // X 8KB @0, Acat 8KB @8192 (64B rows)
  const int b = blockIdx.x;
  const int tt = b & 15, nt = (b >> 4) & 1, ks = b >> 5;
  const int t0 = tt * 128, n0 = nt * 128;
  const int kslice = HID / nks;
  const int k0 = ks * kslice;
  const int wave = tid >> 6, lane = tid & 63;
  const int isx = tid < 128;
  const int row = isx ? tid : tid - 128;
  const size_t gbase = (size_t)((isx ? t0 : n0) + row) * HID + k0;
  const float* srcF = (isx ? (const float*)xv : (const float*)lav) + gbase;
  const unsigned short* srcB =
      (isx ? (const unsigned short*)xv : (const unsigned short*)lav) + gbase;
  char* ldsrow = sm + (isx ? 0 : 8192) + row * 64;
  const int prm = (tid >> 1) & 3;      // (row>>1)&3
  const int wrxb = (isx && nt == 0 && !isb && full);
  unsigned short* xbrow = xb + (size_t)(t0 + row) * HID + k0;

  const int wr = (wave >> 1) * 64, wc = (wave & 1) * 64;
  const int fm = lane & 15, fq = lane >> 4;
  const int sw2 = (fm >> 1) & 3;
  int aO[4], bO[4];
  #pragma unroll
  for (int i = 0; i < 4; ++i) {
    aO[i] = (wr + i * 16 + fm) * 64 + ((fq ^ sw2) << 4);
    bO[i] = 8192 + (wc + i * 16 + fm) * 64 + ((fq ^ sw2) << 4);
  }
  floatx4 acc[4][4];
  #pragma unroll
  for (int i = 0; i < 4; ++i)
    #pragma unroll
    for (int j = 0; j < 4; ++j) acc[i][j] = (floatx4){0.f, 0.f, 0.f, 0.f};

  const int NIT = kslice / 32;
  for (int it = 0; it < NIT; ++it) {
    uint4 w[4];
    if (isb) {
      const uint4* s4 = (const uint4*)(srcB + it * 32);
      #pragma unroll
      for (int g = 0; g < 4; ++g) w[g] = s4[g];
    } else {
      const float4* s4 = (const float4*)(srcF + it * 32);
      #pragma unroll
      for (int g = 0; g < 4; ++g) {
        const float4 f0 = s4[2 * g], f1 = s4[2 * g + 1];
        w[g].x = pk2(f0.x, f0.y); w[g].y = pk2(f0.z, f0.w);
        w[g].z = pk2(f1.x, f1.y); w[g].w = pk2(f1.z, f1.w);
      }
      if (wrxb) {
        uint4* d = (uint4*)(xbrow + it * 32);
        #pragma unroll
        for (int g = 0; g < 4; ++g) d[g] = w[g];
      }
    }
    #pragma unroll
    for (int g = 0; g < 4; ++g)
      *(uint4*)(ldsrow + ((g ^ prm) << 4)) = w[g];
    __syncthreads();
    bf16x8 af[4], bfv[4];
    #pragma unroll
    for (int i = 0; i < 4; ++i) af[i] = *(const bf16x8*)(sm + aO[i]);
    #pragma unroll
    for (int j = 0; j < 4; ++j) bfv[j] = *(const bf16x8*)(sm + bO[j]);
    #pragma unroll
    for (int i = 0; i < 4; ++i)
      #pragma unroll
      for (int j = 0; j < 4; ++j)
        acc[i][j] = __builtin_amdgcn_mfma_f32_16x16x32_bf16(af[i], bfv[j], acc[i][j], 0, 0, 0);
    __syncthreads();
  }
  const int c = lane & 15, rr = (lane >> 4) * 4;
  #pragma unroll
  for (int i = 0; i < 4; ++i)
    #pragma unroll
    for (int r = 0; r < 4; ++r) {
      const int t = t0 + wr + i * 16 + rr + r;
      float* dst = axpart + ((size_t)ks * NTOK + t) * 256 + n0 + wc;
      #pragma unroll
      for (int j = 0; j < 4; ++j) dst[j * 16 + c] = acc[i][j][r];
    }
}

// ============ K-SPLIT main GEMM (69 us proven K-loop) ========================
// 256x256 tile, half-K per block, 8 waves of 128x64, depth-2 counted vmcnt,
// 3x32KB LDS buffers, 0 bank conflicts. P stored NON-TEMPORAL (scalar float,
// legal) so the 64MB of dirty partials don't evict the 4MB/XCD W panel.
__global__ __launch_bounds__(512, 2) void gemm_ks_kernel(
    const void* __restrict__ x_raw, const void* __restrict__ w_raw,
    const unsigned short* __restrict__ xb_ws, const unsigned short* __restrict__ wb_ws,
    float* __restrict__ P) {
  __shared__ char smem[98304];  // buf b @ b*32768: A 16K @0, B 16K @16384
  const int isb = detect_bf16(x_raw);
  const unsigned short* Xb = isb ? (const unsigned short*)x_raw : xb_ws;
  const unsigned short* Wb = isb ? (const unsigned short*)w_raw : wb_ws;

  const int tid = threadIdx.x;
  const int wave = tid >> 6;
  const int lane = tid & 63;
  const int id = blockIdx.x;
  const int xcd = id & 7, slot = id >> 3;           // 0..31
  const int o0 = (xcd * 2 + (slot & 1)) * 256;
  const int t0 = ((slot >> 1) & 7) * 256;
  const int kh = slot >> 4;                          // 0..1
  const int wr = (wave >> 2) * 128;   // 2 row-groups of 128
  const int wc = (wave & 3) * 64;     // 4 col-groups of 64

  const int q_ = ((lane & 3) ^ ((lane >> 3) & 3)) * 16;
  const int srw = (lane >> 2);
  const char* gA = (const char*)Xb + (size_t)(t0 + wave * 32 + srw) * (HID * 2)
                 + q_ + (size_t)kh * 4096;
  const char* gB = (const char*)Wb + (size_t)(o0 + wave * 32 + srw) * (HID * 2)
                 + q_ + (size_t)kh * 4096;

  const int fm = lane & 15, fq = lane >> 4;
  const int sw2 = (fm >> 1) & 3;
  int aOff[8], bOff[4];
  #pragma unroll
  for (int i = 0; i < 8; ++i)
    aOff[i] = (wr + i * 16 + fm) * 64 + ((fq ^ sw2) << 4);
  #pragma unroll
  for (int j = 0; j < 4; ++j)
    bOff[j] = 16384 + (wc + j * 16 + fm) * 64 + ((fq ^ sw2) << 4);
  floatx4 acc[8][4];
  #pragma unroll
  for (int i = 0; i < 8; ++i)
    #pragma unroll
    for (int j = 0; j < 4; ++j) acc[i][j] = (floatx4){0.f, 0.f, 0.f, 0.f};

#define KSTAGE(K, B) do {                                         \
    const size_t kb_ = (size_t)(K) * 64;                          \
    char* d_ = smem + (B) * 32768 + wave * 2048;                  \
    gld16(gA + kb_,                           d_);                \
    gld16(gA + kb_ + 16 * (size_t)HID * 2,    d_ + 1024);         \
    gld16(gB + kb_,                           d_ + 16384);        \
    gld16(gB + kb_ + 16 * (size_t)HID * 2,    d_ + 17408);       \
  } while (0)

#define KCOMPUTE(B) do {                                                        \
    const char* base_ = smem + (B) * 32768;                                     \
    bf16x8 af[8], bfv[4];                                                       \
    _Pragma("unroll")                                                           \
    for (int i = 0; i < 8; ++i) af[i] = *(const bf16x8*)(base_ + aOff[i]);      \
    _Pragma("unroll")                                                           \
    for (int j = 0; j < 4; ++j) bfv[j] = *(const bf16x8*)(base_ + bOff[j]);     \
    _Pragma("unroll")                                                           \
    for (int i = 0; i < 8; ++i)                                                 \
      _Pragma("unroll")                                                         \
      for (int j = 0; j < 4; ++j)                                               \
        acc[i][j] = __builtin_amdgcn_mfma_f32_16x16x32_bf16(af[i], bfv[j], acc[i][j], 0, 0, 0); \
  } while (0)

  const int KITER = (HID / 2) / 32;   // 64 K-steps per half
  int cb = 0, sb = 2;
  KSTAGE(0, 0);
  KSTAGE(1, 1);
  for (int k = 0; k < KITER - 2; ++k) {
    asm volatile("s_waitcnt vmcnt(4)" ::: "memory");
    __builtin_amdgcn_s_barrier();
    KSTAGE(k + 2, sb);
    KCOMPUTE(cb);
    cb = (cb == 2) ? 0 : cb + 1;
    sb = (sb == 2) ? 0 : sb + 1;
  }
  asm volatile("s_waitcnt vmcnt(4)" ::: "memory");
  __builtin_amdgcn_s_barrier();
  KCOMPUTE(cb);
  cb = (cb == 2) ? 0 : cb + 1;
  asm volatile("s_waitcnt vmcnt(0)" ::: "memory");
  __builtin_amdgcn_s_barrier();
  KCOMPUTE(cb);
#undef KSTAGE
#undef KCOMPUTE

  // ---- store f32 partial tile (non-temporal: write-once, never re-read here)
  const int c = lane & 15, rr = (lane >> 4) * 4;
  #pragma unroll
  for (int mi = 0; mi < 8; ++mi) {
    #pragma unroll
    for (int r = 0; r < 4; ++r) {
      const size_t t = t0 + wr + mi * 16 + rr + r;
      float* dst = P + ((size_t)kh * NTOK + t) * NOUT + o0 + wc;
      #pragma unroll
      for (int j = 0; j < 4; ++j)
        __builtin_nontemporal_store(acc[mi][j][r], &dst[j * 16 + c]);
    }
  }
}

// ============ reduce3: high-MLP fold + bias + LoRA epilogue ==================
// Grid 512 x 256 thr (2 blocks/CU — G11: memory-bound wants blocks/CU), patch
// 128t x 128o. Single-pass 16-lora LDS cache (64KB, no half-loop, 1 barrier).
// P read / out written non-temporal (read-once / write-once; keep L2 for the
// axpart & lora_b reuse across blocks).
__global__ __launch_bounds__(256, 2) void reduce3_kernel(
    const void* __restrict__ x_raw, const float* __restrict__ P,
    const void* __restrict__ bias_raw, const void* __restrict__ lorab_raw,
    const float* __restrict__ axpart, const int* __restrict__ idxraw,
    int nks, void* __restrict__ outv) {
  __shared__ char smem[74240];  // Bl 64K @0, axs 8K @65536, tok 512B @73728
  const int isb = detect_bf16(x_raw);
  const int i64 = detect_i64(idxraw);
  const int tid = threadIdx.x;
  const int id = blockIdx.x;
  const int xcd = id & 7, slot = id >> 3;        // slot 0..63
  const int o0 = (xcd * 4 + (slot & 3)) * 128;   // 32 o-tiles of 128
  const int t0 = (slot >> 2) * 128;              // 16 t-tiles of 128
  const int cix = tid & 15;                      // col octet
  const int rix = tid >> 4;                      // row octet 0..15

  // ---- tok + slice-summed ax tables (128 tokens) ----
  {
    const int t_l = tid >> 1, h8 = (tid & 1) * 8;
    const int t = t0 + t_l;
    int l = i64 ? idxraw[2 * t] : idxraw[t];
    if (l < 0 || l >= NLORA) l = -1;
    if ((tid & 1) == 0) *(int*)(smem + 73728 + t_l * 4) = l;
    float4 s0 = make_float4(0.f, 0.f, 0.f, 0.f), s1 = s0;
    if (l >= 0) {
      for (int s = 0; s < nks; ++s) {
        const float4* p = (const float4*)(axpart + ((size_t)s * NTOK + t) * 256 + l * 16 + h8);
        const float4 a = p[0], bq = p[1];
        s0.x += a.x; s0.y += a.y; s0.z += a.z; s0.w += a.w;
        s1.x += bq.x; s1.y += bq.y; s1.z += bq.z; s1.w += bq.w;
      }
    }
    float4* d = (float4*)(smem + 65536 + t_l * 64 + h8 * 4);
    d[0] = s0; d[1] = s1;
  }
  // ---- all 16 loras of B (128 cols) into LDS as rank-pair words ----
  // word(l, rp, col) @ l*4096 + rp*512 + col*4 = bf16(r=2rp) | bf16(r=2rp+1)<<16
  {
    const int lcol = tid & 127, lrh = tid >> 7;   // col, rank-octet half
    #pragma unroll
    for (int l = 0; l < NLORA; ++l) {
      const size_t eoff = ((size_t)l * NOUT + o0 + lcol) * RANK + lrh * 8;
      uint4 pv;
      if (isb) {
        pv = *(const uint4*)((const unsigned short*)lorab_raw + eoff);
      } else {
        const float4* fp = (const float4*)((const float*)lorab_raw + eoff);
        const float4 v0 = fp[0], v1 = fp[1];
        pv.x = pk2(v0.x, v0.y); pv.y = pk2(v0.z, v0.w);
        pv.z = pk2(v1.x, v1.y); pv.w = pk2(v1.z, v1.w);
      }
      unsigned int* wp = (unsigned int*)(smem + l * 4096 + (lrh * 4) * 512 + lcol * 4);
      wp[0] = pv.x; wp[128] = pv.y; wp[256] = pv.z; wp[384] = pv.w;
    }
  }
  // ---- fold P0+P1 (non-temporal, coalesced) while the barrier settles ----
  float acc[8][8];
  float bv[8];
  const int ob = o0 + cix * 8;
  if (isb) {
    #pragma unroll
    for (int k = 0; k < 8; ++k) bv[k] = b2f(((const unsigned short*)bias_raw)[ob + k]);
  } else {
    const float4* bp = (const float4*)((const float*)bias_raw + ob);
    const float4 b0 = bp[0], b1 = bp[1];
    bv[0] = b0.x; bv[1] = b0.y; bv[2] = b0.z; bv[3] = b0.w;
    bv[4] = b1.x; bv[5] = b1.y; bv[6] = b1.z; bv[7] = b1.w;
  }
  #pragma unroll
  for (int rr = 0; rr < 8; ++rr) {
    const size_t row = t0 + rix * 8 + rr;
    const f32x4* p0 = (const f32x4*)(P + row * NOUT + ob);
    const f32x4* p1 = (const f32x4*)(P + ((size_t)NTOK + row) * NOUT + ob);
    const f32x4 a0 = __builtin_nontemporal_load(p0);
    const f32x4 a1 = __builtin_nontemporal_load(p0 + 1);
    const f32x4 c0 = __builtin_nontemporal_load(p1);
    const f32x4 c1 = __builtin_nontemporal_load(p1 + 1);
    #pragma unroll
    for (int w = 0; w < 4; ++w) {
      acc[rr][w] = a0[w] + c0[w];
      acc[rr][4 + w] = a1[w] + c1[w];
    }
  }
  __syncthreads();

  // ---- apply LoRA deltas (single pass over all 16 loras) ----
  #pragma unroll
  for (int rr = 0; rr < 8; ++rr) {
    const int l = *(const int*)(smem + 73728 + (rix * 8 + rr) * 4);
    if (l < 0) continue;
    float axr[16];
    {
      const float4* ap = (const float4*)(smem + 65536 + (rix * 8 + rr) * 64);
      #pragma unroll
      for (int g = 0; g < 4; ++g) {
        const float4 q = ap[g];
        axr[4 * g] = q.x; axr[4 * g + 1] = q.y;
        axr[4 * g + 2] = q.z; axr[4 * g + 3] = q.w;
      }
    }
    const char* bb = smem + l * 4096 + cix * 32;
    #pragma unroll
    for (int rp = 0; rp < 8; ++rp) {
      const uint4 q0 = *(const uint4*)(bb + rp * 512);
      const uint4 q1 = *(const uint4*)(bb + rp * 512 + 16);
      const float a0 = axr[2 * rp], a1 = axr[2 * rp + 1];
      const unsigned int qa[8] = {q0.x, q0.y, q0.z, q0.w, q1.x, q1.y, q1.z, q1.w};
      #pragma unroll
      for (int w = 0; w < 8; ++w) {
        acc[rr][w] += b2f((unsigned short)(qa[w] & 0xFFFF)) * a0
                    + b2f((unsigned short)(qa[w] >> 16)) * a1;
      }
    }
  }

  // ---- store (non-temporal, coalesced) ----
  #pragma unroll
  for (int rr = 0; rr < 8; ++rr) {
    const size_t row = t0 + rix * 8 + rr;
    if (isb) {
      u32x4 pv;
      pv[0] = pk2(acc[rr][0] + bv[0], acc[rr][1] + bv[1]);
      pv[1] = pk2(acc[rr][2] + bv[2], acc[rr][3] + bv[3]);
      pv[2] = pk2(acc[rr][4] + bv[4], acc[rr][5] + bv[5]);
      pv[3] = pk2(acc[rr][6] + bv[6], acc[rr][7] + bv[7]);
      __builtin_nontemporal_store(pv, (u32x4*)((unsigned short*)outv + row * NOUT + ob));
    } else {
      f32x4* of = (f32x4*)((float*)outv + row * NOUT + ob);
      f32x4 v0, v1;
      #pragma unroll
      for (int w = 0; w < 4; ++w) {
        v0[w] = acc[rr][w] + bv[w];
        v1[w] = acc[rr][4 + w] + bv[4 + w];
      }
      __builtin_nontemporal_store(v0, of);
      __builtin_nontemporal_store(v1, of + 1);
    }
  }
}

// ============ fallback main GEMM (R1-exact, 103.8 us proven) =================
__global__ __launch_bounds__(512, 2) void gemm_kernel(
    const void* __restrict__ x_raw, const void* __restrict__ w_raw,
    const unsigned short* __restrict__ xb_ws, const unsigned short* __restrict__ wb_ws,
    const void* __restrict__ bias_raw, const void* __restrict__ lorab_raw,
    const float* __restrict__ axpart, const int* __restrict__ idxraw,
    int nks, void* __restrict__ outv) {
  __shared__ char smem[98304];
  const int isb = detect_bf16(x_raw);
  const int i64 = detect_i64(idxraw);
  const unsigned short* Xb = isb ? (const unsigned short*)x_raw : xb_ws;
  const unsigned short* Wb = isb ? (const unsigned short*)w_raw : wb_ws;

  const int tid = threadIdx.x;
  const int wave = tid >> 6;
  const int lane = tid & 63;
  const int id = blockIdx.x;
  const int xcd = id & 7, slot = id >> 3;
  const int o0 = (xcd * 4 + (slot & 3)) * 128;
  const int t0 = (slot >> 2) * 256;
  const int wr = (wave >> 1) * 64;
  const int wc = (wave & 1) * 64;

  const int q_ = ((lane & 3) ^ ((lane >> 3) & 3)) * 16;
  const int srw = (lane >> 2);
  const char* gA0 = (const char*)Xb + (size_t)(t0 + 0 + wave * 16 + srw) * (HID * 2) + q_;
  const char* gA1 = (const char*)Xb + (size_t)(t0 + 128 + wave * 16 + srw) * (HID * 2) + q_;
  const char* gB0 = (const char*)Wb + (size_t)(o0 + wave * 16 + srw) * (HID * 2) + q_;

  const int fm = lane & 15, fq = lane >> 4;
  const int sw2 = (fm >> 1) & 3;
  int aOff[4], bOff[4];
  #pragma unroll
  for (int i = 0; i < 4; ++i) {
    aOff[i] = (wr + i * 16 + fm) * 64 + ((fq ^ sw2) << 4);
    bOff[i] = 16384 + (wc + i * 16 + fm) * 64 + ((fq ^ sw2) << 4);
  }
  floatx4 acc[4][4];
  #pragma unroll
  for (int i = 0; i < 4; ++i)
    #pragma unroll
    for (int j = 0; j < 4; ++j) acc[i][j] = (floatx4){0.f, 0.f, 0.f, 0.f};

#define STAGE(K, B) do {                                  \
    const size_t kb_ = (size_t)(K) * 64;                  \
    char* d_ = smem + (B) * 24576 + wave * 1024;          \
    gld16(gA0 + kb_, d_);                                 \
    gld16(gA1 + kb_, d_ + 8192);                          \
    gld16(gB0 + kb_, d_ + 16384);                         \
  } while (0)

#define COMPUTE(B) do {                                                         \
    const char* base_ = smem + (B) * 24576;                                     \
    bf16x8 af[4], bfv[4];                                                       \
    _Pragma("unroll")                                                           \
    for (int i = 0; i < 4; ++i) af[i] = *(const bf16x8*)(base_ + aOff[i]);      \
    _Pragma("unroll")                                                           \
    for (int j = 0; j < 4; ++j) bfv[j] = *(const bf16x8*)(base_ + bOff[j]);     \
    __builtin_amdgcn_s_setprio(1);                                              \
    _Pragma("unroll")                                                           \
    for (int i = 0; i < 4; ++i)                                                 \
      _Pragma("unroll")                                                         \
      for (int j = 0; j < 4; ++j)                                               \
        acc[i][j] = __builtin_amdgcn_mfma_f32_16x16x32_bf16(af[i], bfv[j], acc[i][j], 0, 0, 0); \
    __builtin_amdgcn_s_setprio(0);                                              \
  } while (0)

  const int KITER = HID / 32;
  STAGE(0, 0);
  STAGE(1, 1);
  STAGE(2, 2);
  for (int k = 0; k < KITER - 3; ++k) {
    asm volatile("s_waitcnt vmcnt(6)" ::: "memory");
    __builtin_amdgcn_s_barrier();
    STAGE(k + 3, (k + 3) & 3);
    COMPUTE(k & 3);
  }
  asm volatile("s_waitcnt vmcnt(6)" ::: "memory");
  __builtin_amdgcn_s_barrier();
  COMPUTE((KITER - 3) & 3);
  asm volatile("s_waitcnt vmcnt(3)" ::: "memory");
  __builtin_amdgcn_s_barrier();
  COMPUTE((KITER - 2) & 3);
  asm volatile("s_waitcnt vmcnt(0)" ::: "memory");
  __builtin_amdgcn_s_barrier();
  COMPUTE((KITER - 1) & 3);
#undef STAGE
#undef COMPUTE
  __syncthreads();

  {
    const int t_l = tid >> 1, h8 = (tid & 1) * 8;
    const int t = t0 + t_l;
    int l = i64 ? idxraw[2 * t] : idxraw[t];
    if (l < 0 || l >= NLORA) l = -1;
    if ((tid & 1) == 0) *(int*)(smem + 49152 + t_l * 4) = l;
    float4 s0 = make_float4(0.f, 0.f, 0.f, 0.f), s1 = s0;
    if (l >= 0) {
      for (int s = 0; s < nks; ++s) {
        const float4* p = (const float4*)(axpart + ((size_t)s * NTOK + t) * 256 + l * 16 + h8);
        const float4 a = p[0], bq = p[1];
        s0.x += a.x; s0.y += a.y; s0.z += a.z; s0.w += a.w;
        s1.x += bq.x; s1.y += bq.y; s1.z += bq.z; s1.w += bq.w;
      }
    }
    float4* d = (float4*)(smem + 32768 + t_l * 64 + h8 * 4);
    d[0] = s0; d[1] = s1;
  }
  const int c = lane & 15;
  const int rr = (lane >> 4) * 4;
  float bv[4];
  #pragma unroll
  for (int j = 0; j < 4; ++j) {
    const int o = o0 + wc + j * 16 + c;
    bv[j] = isb ? b2f(((const unsigned short*)bias_raw)[o]) : ((const float*)bias_raw)[o];
  }
  const int ol_ld = tid >> 2, rq = (tid & 3) * 4;
  #pragma unroll
  for (int h = 0; h < 2; ++h) {
    __syncthreads();
    #pragma unroll
    for (int lh = 0; lh < 8; ++lh) {
      const int l = h * 8 + lh;
      const size_t eoff = ((size_t)l * NOUT + o0 + ol_ld) * RANK + rq;
      uint2 pv;
      if (isb) {
        pv = *(const uint2*)((const unsigned short*)lorab_raw + eoff);
      } else {
        const float4 v = *(const float4*)((const float*)lorab_raw + eoff);
        pv.x = pk2(v.x, v.y); pv.y = pk2(v.z, v.w);
      }
      *(uint2*)(smem + lh * 4096 + ol_ld * 32 + rq * 2) = pv;
    }
    __syncthreads();
    #pragma unroll
    for (int mi = 0; mi < 4; ++mi) {
      #pragma unroll
      for (int r = 0; r < 4; ++r) {
        const int tl = wr + mi * 16 + rr + r;
        const int l = *(const int*)(smem + 49152 + tl * 4);
        if (l < 0 || (l >> 3) != h) continue;
        float axr[16];
        {
          const float4* ap = (const float4*)(smem + 32768 + tl * 64);
          #pragma unroll
          for (int g = 0; g < 4; ++g) {
            const float4 q = ap[g];
            axr[4 * g] = q.x; axr[4 * g + 1] = q.y;
            axr[4 * g + 2] = q.z; axr[4 * g + 3] = q.w;
          }
        }
        #pragma unroll
        for (int j = 0; j < 4; ++j) {
          const int ol = wc + j * 16 + c;
          const uint4 q0 = *(const uint4*)(smem + (l & 7) * 4096 + ol * 32);
          const uint4 q1 = *(const uint4*)(smem + (l & 7) * 4096 + ol * 32 + 16);
          float d = 0.f;
          const unsigned int qa[8] = {q0.x, q0.y, q0.z, q0.w, q1.x, q1.y, q1.z, q1.w};
          #pragma unroll
          for (int g = 0; g < 8; ++g) {
            d += b2f((unsigned short)(qa[g] & 0xFFFF)) * axr[2 * g];
            d += b2f((unsigned short)(qa[g] >> 16)) * axr[2 * g + 1];
          }
          acc[mi][j][r] += d;
        }
      }
    }
  }
  unsigned short* outb = (unsigned short*)outv;
  float* outf = (float*)outv;
  #pragma unroll
  for (int mi = 0; mi < 4; ++mi) {
    #pragma unroll
    for (int r = 0; r < 4; ++r) {
      const size_t t = t0 + wr + mi * 16 + rr + r;
      #pragma unroll
      for (int j = 0; j < 4; ++j) {
        const int o = o0 + wc + j * 16 + c;
        const float v = acc[mi][j][r] + bv[j];
        const size_t oi = t * NOUT + o;
        if (isb) outb[oi] = f2b(v); else outf[oi] = v;
      }
    }
  }
}

extern "C" void kernel_launch(void* const* d_in, const int* in_sizes, int n_in,
                              void* d_out, int out_size, void* d_ws, size_t ws_size,
                              hipStream_t stream) {
  const void* x  = d_in[0];
  const void* w  = d_in[1];
  const void* bs = d_in[2];
  const void* la = d_in[3];
  const void* lb = d_in[4];
  const int*  ix = (const int*)d_in[5];

  const size_t xb_bytes = (size_t)NTOK * HID * 2;
  const size_t wb_bytes = (size_t)NOUT * HID * 2;
  const size_t ax1      = (size_t)NTOK * 256 * 4;          // one k-slice
  const size_t P_bytes  = (size_t)2 * NTOK * NOUT * 4;     // K-split partials

  char* ws = (char*)d_ws;

  if (ws_size >= xb_bytes + wb_bytes + 8 * ax1 + P_bytes + 64) {
    // K-split path: full-chip 256x256 tiles + high-MLP reduce3 epilogue.
    unsigned short* xb  = (unsigned short*)ws;
    unsigned short* wb2 = (unsigned short*)(ws + xb_bytes);
    float* axp = (float*)(ws + xb_bytes + wb_bytes);
    float* P   = (float*)(ws + xb_bytes + wb_bytes + 8 * ax1);
    prep_kernel<<<32 * 8 + 2048, 256, 0, stream>>>(x, w, la, xb, wb2, axp, 8, 1);
    gemm_ks_kernel<<<256, 512, 0, stream>>>(x, w, xb, wb2, P);
    reduce3_kernel<<<512, 256, 0, stream>>>(x, P, bs, lb, axp, ix, 8, d_out);
    return;
  }

  // fallback ladder (R1-exact path)
  int nks, full;
  unsigned short *xb, *wb2;
  float* axp;
  if (ws_size >= xb_bytes + wb_bytes + 8 * ax1 + 64) {
    nks = 8; full = 1;
    xb = (unsigned short*)ws;
    wb2 = (unsigned short*)(ws + xb_bytes);
    axp = (float*)(ws + xb_bytes + wb_bytes);
  } else if (ws_size >= xb_bytes + wb_bytes + 2 * ax1 + 64) {
    nks = 2; full = 1;
    xb = (unsigned short*)ws;
    wb2 = (unsigned short*)(ws + xb_bytes);
    axp = (float*)(ws + xb_bytes + wb_bytes);
  } else {
    nks = 2; full = 0;
    xb = (unsigned short*)x;
    wb2 = (unsigned short*)w;
    axp = (float*)ws;
  }

  prep_kernel<<<32 * nks + 2048, 256, 0, stream>>>(
      x, w, la, xb, wb2, axp, nks, full);
  gemm_kernel<<<256, 512, 0, stream>>>(
      x, w, xb, wb2, bs, lb, axp, ix, nks, d_out);
}

// Round 9
// 252.394 us; speedup vs baseline: 1.6324x; 1.0916x over previous
//
#include <hip/hip_runtime.h>

#define NTOK 2048
#define HID 4096
#define NOUT 4096
#define NLORA 16
#define RANK 16

typedef float floatx4 __attribute__((ext_vector_type(4)));
typedef __bf16 bf16x8 __attribute__((ext_vector_type(8)));
// native vector types for __builtin_nontemporal_* (HIP float4/uint4 are
// structs and are rejected by the builtin — R7 lesson)
typedef float f32x4 __attribute__((ext_vector_type(4)));
typedef unsigned int u32x4 __attribute__((ext_vector_type(4)));

__device__ __forceinline__ unsigned short f2b(float f) {
  unsigned int u = __float_as_uint(f);
  u += 0x7FFFu + ((u >> 16) & 1u);   // round-to-nearest-even
  return (unsigned short)(u >> 16);
}
__device__ __forceinline__ float b2f(unsigned short u) {
  return __uint_as_float(((unsigned int)u) << 16);
}
__device__ __forceinline__ unsigned int pk2(float a, float b) {
  return (unsigned int)f2b(a) | ((unsigned int)f2b(b) << 16);
}
// f32 <-> f16 via native _Float16 (RTE), no header dependency
__device__ __forceinline__ unsigned short f2h(float f) {
  _Float16 h = (_Float16)f;
  return __builtin_bit_cast(unsigned short, h);
}
__device__ __forceinline__ float h2f(unsigned short u) {
  return (float)__builtin_bit_cast(_Float16, u);
}

// async global->LDS, 16 B/lane; LDS dest is wave-uniform base (+ lane*16 in HW)
__device__ __forceinline__ void gld16(const char* g, char* l) {
  __builtin_amdgcn_global_load_lds(
      (const __attribute__((address_space(1))) unsigned int*)g,
      (__attribute__((address_space(3))) unsigned int*)l,
      16, 0, 0);
}

// ---- inline per-wave dtype detection ----
__device__ __forceinline__ int detect_bf16(const void* xraw) {
  const int lane = threadIdx.x & 63;
  const int e = (((const unsigned short*)xraw)[2 * lane] >> 7) & 0xFF;
  const unsigned long long wild = __ballot(e < 96 || e > 159);
  return wild == 0ull;
}
__device__ __forceinline__ int detect_i64(const int* idxraw) {
  const int lane = threadIdx.x & 63;
  const unsigned long long nz = __ballot((lane & 1) && idxraw[lane] != 0);
  return nz == 0ull;
}

// ============ prep: axall slices (+X conversion side-effect) + W conversion ==
// (R8-verbatim — passed; nt on the read-once W f32 stream only)
__global__ __launch_bounds__(256) void prep_kernel(
    const void* __restrict__ xv, const void* __restrict__ wv,
    const void* __restrict__ lav,
    unsigned short* __restrict__ xb, unsigned short* __restrict__ wb,
    float* __restrict__ axpart, int nks, int full) {
  const int tid = threadIdx.x;
  const int isb = detect_bf16(xv);
  const int AXB = 32 * nks;
  if (blockIdx.x >= AXB) {
    if (isb || !full) return;
    const int W8 = NOUT * HID / 8;
    const int cb = blockIdx.x - AXB;
    for (int i = cb * 256 + tid; i < W8; i += 2048 * 256) {
      const f32x4 a = __builtin_nontemporal_load((const f32x4*)wv + 2 * i);
      const f32x4 b = __builtin_nontemporal_load((const f32x4*)wv + 2 * i + 1);
      u32x4 p;
      p[0] = pk2(a[0], a[1]); p[1] = pk2(a[2], a[3]);
      p[2] = pk2(b[0], b[1]); p[3] = pk2(b[2], b[3]);
      __builtin_nontemporal_store(p, (u32x4*)wb + i);
    }
    return;
  }
  __shared__ char sm[16384];           // X 8KB @0, Acat 8KB @8192 (64B rows)
  const int b = blockIdx.x;
  const int tt = b & 15, nt = (b >> 4) & 1, ks = b >> 5;
  const int t0 = tt * 128, n0 = nt * 128;
  const int kslice = HID / nks;
  const int k0 = ks * kslice;
  const int wave = tid >> 6, lane = tid & 63;
  const int isx = tid < 128;
  const int row = isx ? tid : tid - 128;
  const size_t gbase = (size_t)((isx ? t0 : n0) + row) * HID + k0;
  const float* srcF = (isx ? (const float*)xv : (const float*)lav) + gbase;
  const unsigned short* srcB =
      (isx ? (const unsigned short*)xv : (const unsigned short*)lav) + gbase;
  char* ldsrow = sm + (isx ? 0 : 8192) + row * 64;
  const int prm = (tid >> 1) & 3;      // (row>>1)&3
  const int wrxb = (isx && nt == 0 && !isb && full);
  unsigned short* xbrow = xb + (size_t)(t0 + row) * HID + k0;

  const int wr = (wave >> 1) * 64, wc = (wave & 1) * 64;
  const int fm = lane & 15, fq = lane >> 4;
  const int sw2 = (fm >> 1) & 3;
  int aO[4], bO[4];
  #pragma unroll
  for (int i = 0; i < 4; ++i) {
    aO[i] = (wr + i * 16 + fm) * 64 + ((fq ^ sw2) << 4);
    bO[i] = 8192 + (wc + i * 16 + fm) * 64 + ((fq ^ sw2) << 4);
  }
  floatx4 acc[4][4];
  #pragma unroll
  for (int i = 0; i < 4; ++i)
    #pragma unroll
    for (int j = 0; j < 4; ++j) acc[i][j] = (floatx4){0.f, 0.f, 0.f, 0.f};

  const int NIT = kslice / 32;
  for (int it = 0; it < NIT; ++it) {
    uint4 w[4];
    if (isb) {
      const uint4* s4 = (const uint4*)(srcB + it * 32);
      #pragma unroll
      for (int g = 0; g < 4; ++g) w[g] = s4[g];
    } else {
      const float4* s4 = (const float4*)(srcF + it * 32);
      #pragma unroll
      for (int g = 0; g < 4; ++g) {
        const float4 f0 = s4[2 * g], f1 = s4[2 * g + 1];
        w[g].x = pk2(f0.x, f0.y); w[g].y = pk2(f0.z, f0.w);
        w[g].z = pk2(f1.x, f1.y); w[g].w = pk2(f1.z, f1.w);
      }
      if (wrxb) {
        uint4* d = (uint4*)(xbrow + it * 32);
        #pragma unroll
        for (int g = 0; g < 4; ++g) d[g] = w[g];
      }
    }
    #pragma unroll
    for (int g = 0; g < 4; ++g)
      *(uint4*)(ldsrow + ((g ^ prm) << 4)) = w[g];
    __syncthreads();
    bf16x8 af[4], bfv[4];
    #pragma unroll
    for (int i = 0; i < 4; ++i) af[i] = *(const bf16x8*)(sm + aO[i]);
    #pragma unroll
    for (int j = 0; j < 4; ++j) bfv[j] = *(const bf16x8*)(sm + bO[j]);
    #pragma unroll
    for (int i = 0; i < 4; ++i)
      #pragma unroll
      for (int j = 0; j < 4; ++j)
        acc[i][j] = __builtin_amdgcn_mfma_f32_16x16x32_bf16(af[i], bfv[j], acc[i][j], 0, 0, 0);
    __syncthreads();
  }
  const int c = lane & 15, rr = (lane >> 4) * 4;
  #pragma unroll
  for (int i = 0; i < 4; ++i)
    #pragma unroll
    for (int r = 0; r < 4; ++r) {
      const int t = t0 + wr + i * 16 + rr + r;
      float* dst = axpart + ((size_t)ks * NTOK + t) * 256 + n0 + wc;
      #pragma unroll
      for (int j = 0; j < 4; ++j) dst[j * 16 + c] = acc[i][j][r];
    }
}

// ============ K-SPLIT main GEMM (69 us proven K-loop, R4/R6 store path) ======
// 256x256 tile, half-K per block, 8 waves of 128x64, depth-2 counted vmcnt,
// 3x32KB LDS buffers, 0 bank conflicts. P stored as F16 with REGULAR cached
// stores (R8 lesson: nt stores cost −19% and falsified the eviction theory).
// f16 P = 32MB total = 4MB/XCD — fits per-XCD L2, and both kh-partners plus
// the reduce reader of a given o-range map to the same XCD (o0>>9), so the
// reduce's P reads are L2 hits. f16 rounding of the two half-K partials adds
// ~1e-3 absmax (partials ~N(0,0.5)); bf16 would not be safe, f16 is.
__global__ __launch_bounds__(512, 2) void gemm_ks_kernel(
    const void* __restrict__ x_raw, const void* __restrict__ w_raw,
    const unsigned short* __restrict__ xb_ws, const unsigned short* __restrict__ wb_ws,
    unsigned short* __restrict__ P) {
  __shared__ char smem[98304];  // buf b @ b*32768: A 16K @0, B 16K @16384
  const int isb = detect_bf16(x_raw);
  const unsigned short* Xb = isb ? (const unsigned short*)x_raw : xb_ws;
  const unsigned short* Wb = isb ? (const unsigned short*)w_raw : wb_ws;

  const int tid = threadIdx.x;
  const int wave = tid >> 6;
  const int lane = tid & 63;
  const int id = blockIdx.x;
  const int xcd = id & 7, slot = id >> 3;           // 0..31
  const int o0 = (xcd * 2 + (slot & 1)) * 256;
  const int t0 = ((slot >> 1) & 7) * 256;
  const int kh = slot >> 4;                          // 0..1
  const int wr = (wave >> 2) * 128;   // 2 row-groups of 128
  const int wc = (wave & 3) * 64;     // 4 col-groups of 64

  const int q_ = ((lane & 3) ^ ((lane >> 3) & 3)) * 16;
  const int srw = (lane >> 2);
  const char* gA = (const char*)Xb + (size_t)(t0 + wave * 32 + srw) * (HID * 2)
                 + q_ + (size_t)kh * 4096;
  const char* gB = (const char*)Wb + (size_t)(o0 + wave * 32 + srw) * (HID * 2)
                 + q_ + (size_t)kh * 4096;

  const int fm = lane & 15, fq = lane >> 4;
  const int sw2 = (fm >> 1) & 3;
  int aOff[8], bOff[4];
  #pragma unroll
  for (int i = 0; i < 8; ++i)
    aOff[i] = (wr + i * 16 + fm) * 64 + ((fq ^ sw2) << 4);
  #pragma unroll
  for (int j = 0; j < 4; ++j)
    bOff[j] = 16384 + (wc + j * 16 + fm) * 64 + ((fq ^ sw2) << 4);
  floatx4 acc[8][4];
  #pragma unroll
  for (int i = 0; i < 8; ++i)
    #pragma unroll
    for (int j = 0; j < 4; ++j) acc[i][j] = (floatx4){0.f, 0.f, 0.f, 0.f};

#define KSTAGE(K, B) do {                                         \
    const size_t kb_ = (size_t)(K) * 64;                          \
    char* d_ = smem + (B) * 32768 + wave * 2048;                  \
    gld16(gA + kb_,                           d_);                \
    gld16(gA + kb_ + 16 * (size_t)HID * 2,    d_ + 1024);         \
    gld16(gB + kb_,                           d_ + 16384);        \
    gld16(gB + kb_ + 16 * (size_t)HID * 2,    d_ + 17408);       \
  } while (0)

#define KCOMPUTE(B) do {                                                        \
    const char* base_ = smem + (B) * 32768;                                     \
    bf16x8 af[8], bfv[4];                                                       \
    _Pragma("unroll")                                                           \
    for (int i = 0; i < 8; ++i) af[i] = *(const bf16x8*)(base_ + aOff[i]);      \
    _Pragma("unroll")                                                           \
    for (int j = 0; j < 4; ++j) bfv[j] = *(const bf16x8*)(base_ + bOff[j]);     \
    _Pragma("unroll")                                                           \
    for (int i = 0; i < 8; ++i)                                                 \
      _Pragma("unroll")                                                         \
      for (int j = 0; j < 4; ++j)                                               \
        acc[i][j] = __builtin_amdgcn_mfma_f32_16x16x32_bf16(af[i], bfv[j], acc[i][j], 0, 0, 0); \
  } while (0)

  const int KITER = (HID / 2) / 32;   // 64 K-steps per half
  int cb = 0, sb = 2;
  KSTAGE(0, 0);
  KSTAGE(1, 1);
  for (int k = 0; k < KITER - 2; ++k) {
    asm volatile("s_waitcnt vmcnt(4)" ::: "memory");
    __builtin_amdgcn_s_barrier();
    KSTAGE(k + 2, sb);
    KCOMPUTE(cb);
    cb = (cb == 2) ? 0 : cb + 1;
    sb = (sb == 2) ? 0 : sb + 1;
  }
  asm volatile("s_waitcnt vmcnt(4)" ::: "memory");
  __builtin_amdgcn_s_barrier();
  KCOMPUTE(cb);
  cb = (cb == 2) ? 0 : cb + 1;
  asm volatile("s_waitcnt vmcnt(0)" ::: "memory");
  __builtin_amdgcn_s_barrier();
  KCOMPUTE(cb);
#undef KSTAGE
#undef KCOMPUTE

  // ---- store f16 partial tile (regular cached stores -> L2-resident) ----
  const int c = lane & 15, rr = (lane >> 4) * 4;
  #pragma unroll
  for (int mi = 0; mi < 8; ++mi) {
    #pragma unroll
    for (int r = 0; r < 4; ++r) {
      const size_t t = t0 + wr + mi * 16 + rr + r;
      unsigned short* dst = P + ((size_t)kh * NTOK + t) * NOUT + o0 + wc;
      #pragma unroll
      for (int j = 0; j < 4; ++j)
        dst[j * 16 + c] = f2h(acc[mi][j][r]);
    }
  }
}

// ============ reduce3: fold f16 partials + bias + LoRA epilogue ==============
// Grid 512 x 256 thr (2 blocks/CU), patch 128t x 128o. Single-pass 16-lora
// LDS cache (64KB). P read with REGULAR loads (L2-hit: 4MB/XCD, XCD-aligned
// o-mapping o0>>9 matches the gemm's). out written nt (write-once).
__global__ __launch_bounds__(256, 2) void reduce3_kernel(
    const void* __restrict__ x_raw, const unsigned short* __restrict__ P,
    const void* __restrict__ bias_raw, const void* __restrict__ lorab_raw,
    const float* __restrict__ axpart, const int* __restrict__ idxraw,
    int nks, void* __restrict__ outv) {
  __shared__ char smem[74240];  // Bl 64K @0, axs 8K @65536, tok 512B @73728
  const int isb = detect_bf16(x_raw);
  const int i64 = detect_i64(idxraw);
  const int tid = threadIdx.x;
  const int id = blockIdx.x;
  const int xcd = id & 7, slot = id >> 3;        // slot 0..63
  const int o0 = (xcd * 4 + (slot & 3)) * 128;   // 32 o-tiles of 128
  const int t0 = (slot >> 2) * 128;              // 16 t-tiles of 128
  const int cix = tid & 15;                      // col octet
  const int rix = tid >> 4;                      // row octet 0..15

  // ---- tok + slice-summed ax tables (128 tokens) ----
  {
    const int t_l = tid >> 1, h8 = (tid & 1) * 8;
    const int t = t0 + t_l;
    int l = i64 ? idxraw[2 * t] : idxraw[t];
    if (l < 0 || l >= NLORA) l = -1;
    if ((tid & 1) == 0) *(int*)(smem + 73728 + t_l * 4) = l;
    float4 s0 = make_float4(0.f, 0.f, 0.f, 0.f), s1 = s0;
    if (l >= 0) {
      for (int s = 0; s < nks; ++s) {
        const float4* p = (const float4*)(axpart + ((size_t)s * NTOK + t) * 256 + l * 16 + h8);
        const float4 a = p[0], bq = p[1];
        s0.x += a.x; s0.y += a.y; s0.z += a.z; s0.w += a.w;
        s1.x += bq.x; s1.y += bq.y; s1.z += bq.z; s1.w += bq.w;
      }
    }
    float4* d = (float4*)(smem + 65536 + t_l * 64 + h8 * 4);
    d[0] = s0; d[1] = s1;
  }
  // ---- all 16 loras of B (128 cols) into LDS as rank-pair words ----
  // word(l, rp, col) @ l*4096 + rp*512 + col*4 = bf16(r=2rp) | bf16(r=2rp+1)<<16
  {
    const int lcol = tid & 127, lrh = tid >> 7;   // col, rank-octet half
    #pragma unroll
    for (int l = 0; l < NLORA; ++l) {
      const size_t eoff = ((size_t)l * NOUT + o0 + lcol) * RANK + lrh * 8;
      uint4 pv;
      if (isb) {
        pv = *(const uint4*)((const unsigned short*)lorab_raw + eoff);
      } else {
        const float4* fp = (const float4*)((const float*)lorab_raw + eoff);
        const float4 v0 = fp[0], v1 = fp[1];
        pv.x = pk2(v0.x, v0.y); pv.y = pk2(v0.z, v0.w);
        pv.z = pk2(v1.x, v1.y); pv.w = pk2(v1.z, v1.w);
      }
      unsigned int* wp = (unsigned int*)(smem + l * 4096 + (lrh * 4) * 512 + lcol * 4);
      wp[0] = pv.x; wp[128] = pv.y; wp[256] = pv.z; wp[384] = pv.w;
    }
  }
  // ---- fold f16 P0+P1 (coalesced 16B loads) + bias ----
  float acc[8][8];
  float bv[8];
  const int ob = o0 + cix * 8;
  if (isb) {
    #pragma unroll
    for (int k = 0; k < 8; ++k) bv[k] = b2f(((const unsigned short*)bias_raw)[ob + k]);
  } else {
    const float4* bp = (const float4*)((const float*)bias_raw + ob);
    const float4 b0 = bp[0], b1 = bp[1];
    bv[0] = b0.x; bv[1] = b0.y; bv[2] = b0.z; bv[3] = b0.w;
    bv[4] = b1.x; bv[5] = b1.y; bv[6] = b1.z; bv[7] = b1.w;
  }
  #pragma unroll
  for (int rr = 0; rr < 8; ++rr) {
    const size_t row = t0 + rix * 8 + rr;
    const uint4 a = *(const uint4*)(P + row * NOUT + ob);
    const uint4 cc = *(const uint4*)(P + ((size_t)NTOK + row) * NOUT + ob);
    const unsigned int aw[4] = {a.x, a.y, a.z, a.w};
    const unsigned int cw[4] = {cc.x, cc.y, cc.z, cc.w};
    #pragma unroll
    for (int g = 0; g < 4; ++g) {
      acc[rr][2 * g]     = h2f((unsigned short)(aw[g] & 0xFFFF))
                         + h2f((unsigned short)(cw[g] & 0xFFFF));
      acc[rr][2 * g + 1] = h2f((unsigned short)(aw[g] >> 16))
                         + h2f((unsigned short)(cw[g] >> 16));
    }
  }
  __syncthreads();

  // ---- apply LoRA deltas (single pass over all 16 loras) ----
  #pragma unroll
  for (int rr = 0; rr < 8; ++rr) {
    const int l = *(const int*)(smem + 73728 + (rix * 8 + rr) * 4);
    if (l < 0) continue;
    float axr[16];
    {
      const float4* ap = (const float4*)(smem + 65536 + (rix * 8 + rr) * 64);
      #pragma unroll
      for (int g = 0; g < 4; ++g) {
        const float4 q = ap[g];
        axr[4 * g] = q.x; axr[4 * g + 1] = q.y;
        axr[4 * g + 2] = q.z; axr[4 * g + 3] = q.w;
      }
    }
    const char* bb = smem + l * 4096 + cix * 32;
    #pragma unroll
    for (int rp = 0; rp < 8; ++rp) {
      const uint4 q0 = *(const uint4*)(bb + rp * 512);
      const uint4 q1 = *(const uint4*)(bb + rp * 512 + 16);
      const float a0 = axr[2 * rp], a1 = axr[2 * rp + 1];
      const unsigned int qa[8] = {q0.x, q0.y, q0.z, q0.w, q1.x, q1.y, q1.z, q1.w};
      #pragma unroll
      for (int w = 0; w < 8; ++w) {
        acc[rr][w] += b2f((unsigned short)(qa[w] & 0xFFFF)) * a0
                    + b2f((unsigned short)(qa[w] >> 16)) * a1;
      }
    }
  }

  // ---- store (non-temporal, coalesced) ----
  #pragma unroll
  for (int rr = 0; rr < 8; ++rr) {
    const size_t row = t0 + rix * 8 + rr;
    if (isb) {
      u32x4 pv;
      pv[0] = pk2(acc[rr][0] + bv[0], acc[rr][1] + bv[1]);
      pv[1] = pk2(acc[rr][2] + bv[2], acc[rr][3] + bv[3]);
      pv[2] = pk2(acc[rr][4] + bv[4], acc[rr][5] + bv[5]);
      pv[3] = pk2(acc[rr][6] + bv[6], acc[rr][7] + bv[7]);
      __builtin_nontemporal_store(pv, (u32x4*)((unsigned short*)outv + row * NOUT + ob));
    } else {
      f32x4* of = (f32x4*)((float*)outv + row * NOUT + ob);
      f32x4 v0, v1;
      #pragma unroll
      for (int w = 0; w < 4; ++w) {
        v0[w] = acc[rr][w] + bv[w];
        v1[w] = acc[rr][4 + w] + bv[4 + w];
      }
      __builtin_nontemporal_store(v0, of);
      __builtin_nontemporal_store(v1, of + 1);
    }
  }
}

// ============ fallback main GEMM (R1-exact, 103.8 us proven) =================
__global__ __launch_bounds__(512, 2) void gemm_kernel(
    const void* __restrict__ x_raw, const void* __restrict__ w_raw,
    const unsigned short* __restrict__ xb_ws, const unsigned short* __restrict__ wb_ws,
    const void* __restrict__ bias_raw, const void* __restrict__ lorab_raw,
    const float* __restrict__ axpart, const int* __restrict__ idxraw,
    int nks, void* __restrict__ outv) {
  __shared__ char smem[98304];
  const int isb = detect_bf16(x_raw);
  const int i64 = detect_i64(idxraw);
  const unsigned short* Xb = isb ? (const unsigned short*)x_raw : xb_ws;
  const unsigned short* Wb = isb ? (const unsigned short*)w_raw : wb_ws;

  const int tid = threadIdx.x;
  const int wave = tid >> 6;
  const int lane = tid & 63;
  const int id = blockIdx.x;
  const int xcd = id & 7, slot = id >> 3;
  const int o0 = (xcd * 4 + (slot & 3)) * 128;
  const int t0 = (slot >> 2) * 256;
  const int wr = (wave >> 1) * 64;
  const int wc = (wave & 1) * 64;

  const int q_ = ((lane & 3) ^ ((lane >> 3) & 3)) * 16;
  const int srw = (lane >> 2);
  const char* gA0 = (const char*)Xb + (size_t)(t0 + 0 + wave * 16 + srw) * (HID * 2) + q_;
  const char* gA1 = (const char*)Xb + (size_t)(t0 + 128 + wave * 16 + srw) * (HID * 2) + q_;
  const char* gB0 = (const char*)Wb + (size_t)(o0 + wave * 16 + srw) * (HID * 2) + q_;

  const int fm = lane & 15, fq = lane >> 4;
  const int sw2 = (fm >> 1) & 3;
  int aOff[4], bOff[4];
  #pragma unroll
  for (int i = 0; i < 4; ++i) {
    aOff[i] = (wr + i * 16 + fm) * 64 + ((fq ^ sw2) << 4);
    bOff[i] = 16384 + (wc + i * 16 + fm) * 64 + ((fq ^ sw2) << 4);
  }
  floatx4 acc[4][4];
  #pragma unroll
  for (int i = 0; i < 4; ++i)
    #pragma unroll
    for (int j = 0; j < 4; ++j) acc[i][j] = (floatx4){0.f, 0.f, 0.f, 0.f};

#define STAGE(K, B) do {                                  \
    const size_t kb_ = (size_t)(K) * 64;                  \
    char* d_ = smem + (B) * 24576 + wave * 1024;          \
    gld16(gA0 + kb_, d_);                                 \
    gld16(gA1 + kb_, d_ + 8192);                          \
    gld16(gB0 + kb_, d_ + 16384);                         \
  } while (0)

#define COMPUTE(B) do {                                                         \
    const char* base_ = smem + (B) * 24576;                                     \
    bf16x8 af[4], bfv[4];                                                       \
    _Pragma("unroll")                                                           \
    for (int i = 0; i < 4; ++i) af[i] = *(const bf16x8*)(base_ + aOff[i]);      \
    _Pragma("unroll")                                                           \
    for (int j = 0; j < 4; ++j) bfv[j] = *(const bf16x8*)(base_ + bOff[j]);     \
    __builtin_amdgcn_s_setprio(1);                                              \
    _Pragma("unroll")                                                           \
    for (int i = 0; i < 4; ++i)                                                 \
      _Pragma("unroll")                                                         \
      for (int j = 0; j < 4; ++j)                                               \
        acc[i][j] = __builtin_amdgcn_mfma_f32_16x16x32_bf16(af[i], bfv[j], acc[i][j], 0, 0, 0); \
    __builtin_amdgcn_s_setprio(0);                                              \
  } while (0)

  const int KITER = HID / 32;
  STAGE(0, 0);
  STAGE(1, 1);
  STAGE(2, 2);
  for (int k = 0; k < KITER - 3; ++k) {
    asm volatile("s_waitcnt vmcnt(6)" ::: "memory");
    __builtin_amdgcn_s_barrier();
    STAGE(k + 3, (k + 3) & 3);
    COMPUTE(k & 3);
  }
  asm volatile("s_waitcnt vmcnt(6)" ::: "memory");
  __builtin_amdgcn_s_barrier();
  COMPUTE((KITER - 3) & 3);
  asm volatile("s_waitcnt vmcnt(3)" ::: "memory");
  __builtin_amdgcn_s_barrier();
  COMPUTE((KITER - 2) & 3);
  asm volatile("s_waitcnt vmcnt(0)" ::: "memory");
  __builtin_amdgcn_s_barrier();
  COMPUTE((KITER - 1) & 3);
#undef STAGE
#undef COMPUTE
  __syncthreads();

  {
    const int t_l = tid >> 1, h8 = (tid & 1) * 8;
    const int t = t0 + t_l;
    int l = i64 ? idxraw[2 * t] : idxraw[t];
    if (l < 0 || l >= NLORA) l = -1;
    if ((tid & 1) == 0) *(int*)(smem + 49152 + t_l * 4) = l;
    float4 s0 = make_float4(0.f, 0.f, 0.f, 0.f), s1 = s0;
    if (l >= 0) {
      for (int s = 0; s < nks; ++s) {
        const float4* p = (const float4*)(axpart + ((size_t)s * NTOK + t) * 256 + l * 16 + h8);
        const float4 a = p[0], bq = p[1];
        s0.x += a.x; s0.y += a.y; s0.z += a.z; s0.w += a.w;
        s1.x += bq.x; s1.y += bq.y; s1.z += bq.z; s1.w += bq.w;
      }
    }
    float4* d = (float4*)(smem + 32768 + t_l * 64 + h8 * 4);
    d[0] = s0; d[1] = s1;
  }
  const int c = lane & 15;
  const int rr = (lane >> 4) * 4;
  float bv[4];
  #pragma unroll
  for (int j = 0; j < 4; ++j) {
    const int o = o0 + wc + j * 16 + c;
    bv[j] = isb ? b2f(((const unsigned short*)bias_raw)[o]) : ((const float*)bias_raw)[o];
  }
  const int ol_ld = tid >> 2, rq = (tid & 3) * 4;
  #pragma unroll
  for (int h = 0; h < 2; ++h) {
    __syncthreads();
    #pragma unroll
    for (int lh = 0; lh < 8; ++lh) {
      const int l = h * 8 + lh;
      const size_t eoff = ((size_t)l * NOUT + o0 + ol_ld) * RANK + rq;
      uint2 pv;
      if (isb) {
        pv = *(const uint2*)((const unsigned short*)lorab_raw + eoff);
      } else {
        const float4 v = *(const float4*)((const float*)lorab_raw + eoff);
        pv.x = pk2(v.x, v.y); pv.y = pk2(v.z, v.w);
      }
      *(uint2*)(smem + lh * 4096 + ol_ld * 32 + rq * 2) = pv;
    }
    __syncthreads();
    #pragma unroll
    for (int mi = 0; mi < 4; ++mi) {
      #pragma unroll
      for (int r = 0; r < 4; ++r) {
        const int tl = wr + mi * 16 + rr + r;
        const int l = *(const int*)(smem + 49152 + tl * 4);
        if (l < 0 || (l >> 3) != h) continue;
        float axr[16];
        {
          const float4* ap = (const float4*)(smem + 32768 + tl * 64);
          #pragma unroll
          for (int g = 0; g < 4; ++g) {
            const float4 q = ap[g];
            axr[4 * g] = q.x; axr[4 * g + 1] = q.y;
            axr[4 * g + 2] = q.z; axr[4 * g + 3] = q.w;
          }
        }
        #pragma unroll
        for (int j = 0; j < 4; ++j) {
          const int ol = wc + j * 16 + c;
          const uint4 q0 = *(const uint4*)(smem + (l & 7) * 4096 + ol * 32);
          const uint4 q1 = *(const uint4*)(smem + (l & 7) * 4096 + ol * 32 + 16);
          float d = 0.f;
          const unsigned int qa[8] = {q0.x, q0.y, q0.z, q0.w, q1.x, q1.y, q1.z, q1.w};
          #pragma unroll
          for (int g = 0; g < 8; ++g) {
            d += b2f((unsigned short)(qa[g] & 0xFFFF)) * axr[2 * g];
            d += b2f((unsigned short)(qa[g] >> 16)) * axr[2 * g + 1];
          }
          acc[mi][j][r] += d;
        }
      }
    }
  }
  unsigned short* outb = (unsigned short*)outv;
  float* outf = (float*)outv;
  #pragma unroll
  for (int mi = 0; mi < 4; ++mi) {
    #pragma unroll
    for (int r = 0; r < 4; ++r) {
      const size_t t = t0 + wr + mi * 16 + rr + r;
      #pragma unroll
      for (int j = 0; j < 4; ++j) {
        const int o = o0 + wc + j * 16 + c;
        const float v = acc[mi][j][r] + bv[j];
        const size_t oi = t * NOUT + o;
        if (isb) outb[oi] = f2b(v); else outf[oi] = v;
      }
    }
  }
}

extern "C" void kernel_launch(void* const* d_in, const int* in_sizes, int n_in,
                              void* d_out, int out_size, void* d_ws, size_t ws_size,
                              hipStream_t stream) {
  const void* x  = d_in[0];
  const void* w  = d_in[1];
  const void* bs = d_in[2];
  const void* la = d_in[3];
  const void* lb = d_in[4];
  const int*  ix = (const int*)d_in[5];

  const size_t xb_bytes = (size_t)NTOK * HID * 2;
  const size_t wb_bytes = (size_t)NOUT * HID * 2;
  const size_t ax1      = (size_t)NTOK * 256 * 4;          // one k-slice
  const size_t P_bytes  = (size_t)2 * NTOK * NOUT * 2;     // f16 K-split partials

  char* ws = (char*)d_ws;

  if (ws_size >= xb_bytes + wb_bytes + 8 * ax1 + P_bytes + 64) {
    // K-split path: full-chip 256x256 tiles + f16-P reduce3 epilogue.
    unsigned short* xb  = (unsigned short*)ws;
    unsigned short* wb2 = (unsigned short*)(ws + xb_bytes);
    float* axp = (float*)(ws + xb_bytes + wb_bytes);
    unsigned short* P = (unsigned short*)(ws + xb_bytes + wb_bytes + 8 * ax1);
    prep_kernel<<<32 * 8 + 2048, 256, 0, stream>>>(x, w, la, xb, wb2, axp, 8, 1);
    gemm_ks_kernel<<<256, 512, 0, stream>>>(x, w, xb, wb2, P);
    reduce3_kernel<<<512, 256, 0, stream>>>(x, P, bs, lb, axp, ix, 8, d_out);
    return;
  }

  // fallback ladder (R1-exact path)
  int nks, full;
  unsigned short *xb, *wb2;
  float* axp;
  if (ws_size >= xb_bytes + wb_bytes + 8 * ax1 + 64) {
    nks = 8; full = 1;
    xb = (unsigned short*)ws;
    wb2 = (unsigned short*)(ws + xb_bytes);
    axp = (float*)(ws + xb_bytes + wb_bytes);
  } else if (ws_size >= xb_bytes + wb_bytes + 2 * ax1 + 64) {
    nks = 2; full = 1;
    xb = (unsigned short*)ws;
    wb2 = (unsigned short*)(ws + xb_bytes);
    axp = (float*)(ws + xb_bytes + wb_bytes);
  } else {
    nks = 2; full = 0;
    xb = (unsigned short*)x;
    wb2 = (unsigned short*)w;
    axp = (float*)ws;
  }

  prep_kernel<<<32 * nks + 2048, 256, 0, stream>>>(
      x, w, la, xb, wb2, axp, nks, full);
  gemm_kernel<<<256, 512, 0, stream>>>(
      x, w, xb, wb2, bs, lb, axp, ix, nks, d_out);
}